// Round 16
// baseline (505.065 us; speedup 1.0000x reference)
//
#include <hip/hip_runtime.h>
#include <math.h>

typedef __bf16 bf16;
typedef bf16  bf16x8 __attribute__((ext_vector_type(8)));
typedef bf16  bf16x4 __attribute__((ext_vector_type(4)));
typedef bf16  bf16x2 __attribute__((ext_vector_type(2)));
typedef float f32x4  __attribute__((ext_vector_type(4)));

#define BSH2 8        // bucket = 256 nodes
#define PCH  8192     // edges per partition chunk
#define CAP  4608     // LDS record capacity per bucket (mean 4096, 8 sigma margin)

// ---------------- degree / norm precompute ----------------

__global__ void zero_i32(int* __restrict__ p, int n) {
    int i = blockIdx.x * blockDim.x + threadIdx.x;
    if (i < n) p[i] = 0;
}

__global__ void count_deg(const int* __restrict__ dst, int* __restrict__ deg, int E) {
    int i = blockIdx.x * blockDim.x + threadIdx.x;
    int stride = gridDim.x * blockDim.x;
    for (; i < E; i += stride) atomicAdd(&deg[dst[i]], 1);
}

__global__ void finalize_dinv(const int* __restrict__ deg, float* __restrict__ dinv, int n) {
    int i = blockIdx.x * blockDim.x + threadIdx.x;
    if (i < n) dinv[i] = rsqrtf((float)deg[i] + 1.0f);   // +1 self-loop
}

// ---------------- parallel 3-phase exclusive scan (node offsets) ----------------
#define SCHUNK 2048

__global__ __launch_bounds__(256) void scan_p1(const int* __restrict__ deg,
                                               int* __restrict__ bsum, int n) {
    int base = blockIdx.x * SCHUNK;
    int s = 0;
    for (int i = threadIdx.x; i < SCHUNK; i += 256) {
        int idx = base + i;
        s += (idx < n) ? deg[idx] : 0;
    }
    #pragma unroll
    for (int o = 32; o >= 1; o >>= 1) s += __shfl_xor(s, o, 64);
    __shared__ int ws[4];
    if ((threadIdx.x & 63) == 0) ws[threadIdx.x >> 6] = s;
    __syncthreads();
    if (threadIdx.x == 0) bsum[blockIdx.x] = ws[0] + ws[1] + ws[2] + ws[3];
}

__global__ __launch_bounds__(64) void scan_p2(int* __restrict__ bsum,
                                              int* __restrict__ off, int nb, int n) {
    int lane = threadIdx.x;
    __shared__ int carry_s;
    if (lane == 0) carry_s = 0;
    __syncthreads();
    for (int base = 0; base < nb; base += 64) {
        int i = base + lane;
        int v = (i < nb) ? bsum[i] : 0;
        int x = v;
        #pragma unroll
        for (int o = 1; o < 64; o <<= 1) {
            int t = __shfl_up(x, o, 64);
            if (lane >= o) x += t;
        }
        int carry = carry_s;
        if (i < nb) bsum[i] = carry + x - v;   // exclusive
        int total = __shfl(x, 63, 64);
        __syncthreads();
        if (lane == 0) carry_s = carry + total;
        __syncthreads();
    }
    if (lane == 0) off[n] = carry_s;
}

__global__ __launch_bounds__(256) void scan_p3(const int* __restrict__ deg,
                                               const int* __restrict__ bsum,
                                               int* __restrict__ off,
                                               int* __restrict__ cursor, int n) {
    int base = blockIdx.x * SCHUNK + (int)threadIdx.x * 8;
    int v[8]; int s = 0;
    #pragma unroll
    for (int j = 0; j < 8; j++) {
        int idx = base + j;
        v[j] = (idx < n) ? deg[idx] : 0;
        s += v[j];
    }
    int lane = threadIdx.x & 63, wv = threadIdx.x >> 6;
    int x = s;
    #pragma unroll
    for (int o = 1; o < 64; o <<= 1) {
        int t = __shfl_up(x, o, 64);
        if (lane >= o) x += t;
    }
    __shared__ int wsum[4];
    if (lane == 63) wsum[wv] = x;
    __syncthreads();
    int wbase = 0;
    #pragma unroll
    for (int w = 0; w < 4; w++) if (w < wv) wbase += wsum[w];
    int tbase = bsum[blockIdx.x] + wbase + x - s;   // exclusive prefix for this thread
    #pragma unroll
    for (int j = 0; j < 8; j++) {
        int idx = base + j;
        if (idx < n) { off[idx] = tbase; cursor[idx] = 0; tbase += v[j]; }
    }
}

// ---------------- pass 1: partition edges by dst bucket (dst>>8), coalesced runs ----------------

__global__ __launch_bounds__(256) void partition_edges(
    const int* __restrict__ src, const int* __restrict__ dst,
    const int* __restrict__ off, int* __restrict__ bcur,
    uint2* __restrict__ ebuf, int E, int n, int nbk)
{
    __shared__ int lhist[512];
    __shared__ int lbase[512];
    __shared__ int lcur[512];
    __shared__ int gbase[512];
    __shared__ int csum[8];
    __shared__ unsigned short stage[PCH];   // 16 KB

    const int tid = threadIdx.x, lane = tid & 63, wv = tid >> 6;

    for (int base = blockIdx.x * PCH; base < E; base += gridDim.x * PCH) {
        const int cnt = min(PCH, E - base);

        for (int b = tid; b < 512; b += 256) lhist[b] = 0;
        __syncthreads();
        for (int i = tid; i < cnt; i += 256)
            atomicAdd(&lhist[dst[base + i] >> BSH2], 1);
        __syncthreads();
        for (int c = wv; c < 8; c += 4) {
            int idx = c * 64 + lane;
            int v = lhist[idx], x = v;
            #pragma unroll
            for (int o = 1; o < 64; o <<= 1) {
                int t = __shfl_up(x, o, 64);
                if (lane >= o) x += t;
            }
            lbase[idx] = x - v;
            if (lane == 63) csum[c] = x;
        }
        __syncthreads();
        if (tid == 0) {
            int acc = 0;
            #pragma unroll
            for (int c = 0; c < 8; c++) { int t = csum[c]; csum[c] = acc; acc += t; }
        }
        __syncthreads();
        for (int c = wv; c < 8; c += 4) {
            int idx = c * 64 + lane;
            lbase[idx] += csum[c];
            lcur[idx] = lbase[idx];
        }
        __syncthreads();
        for (int i = tid; i < cnt; i += 256) {
            int b = dst[base + i] >> BSH2;
            int p = atomicAdd(&lcur[b], 1);
            stage[p] = (unsigned short)i;
        }
        __syncthreads();
        for (int b = tid; b < nbk; b += 256) {
            int cb = lbase[b + 1] - lbase[b];
            if (cb > 0) gbase[b] = off[b << BSH2] + atomicAdd(&bcur[b], cb);
        }
        __syncthreads();
        for (int k = tid; k < cnt; k += 256) {
            int i = base + (int)stage[k];
            int s = src[i], d = dst[i];
            int b = d >> BSH2;
            ebuf[gbase[b] + (k - lbase[b])] = make_uint2((unsigned)s, (unsigned)d);
        }
        __syncthreads();
    }
}

// ---------------- pass 2: per-bucket LDS counting sort -> coalesced erec write ----------------

__global__ __launch_bounds__(256) void fill_sort(
    const uint2* __restrict__ ebuf, const int* __restrict__ off,
    const float* __restrict__ dinv, int* __restrict__ gcur,
    uint2* __restrict__ erec, int n, int nbk)
{
    __shared__ int  lcur[256];
    __shared__ uint2 lrec[CAP];   // 36 KB

    for (int b = blockIdx.x; b < nbk; b += gridDim.x) {
        const int n0 = b << BSH2;
        const int n1 = min(n0 + 256, n);
        const int e0 = off[n0], e1 = off[n1];
        const int cnt = e1 - e0;
        if (threadIdx.x < (unsigned)(n1 - n0))
            lcur[threadIdx.x] = off[n0 + threadIdx.x] - e0;
        __syncthreads();
        if (cnt <= CAP) {
            for (int i = threadIdx.x; i < cnt; i += 256) {
                uint2 q = ebuf[e0 + i];
                int s = (int)q.x, d = (int)q.y;
                int p = atomicAdd(&lcur[d - n0], 1);
                lrec[p] = make_uint2(q.x, (unsigned)__float_as_uint(dinv[s] * dinv[d]));
            }
            __syncthreads();
            for (int i = threadIdx.x; i < cnt; i += 256)
                erec[e0 + i] = lrec[i];
        } else {
            for (int i = threadIdx.x; i < cnt; i += 256) {
                uint2 q = ebuf[e0 + i];
                int s = (int)q.x, d = (int)q.y;
                int p = off[d] + atomicAdd(&gcur[d], 1);
                erec[p] = make_uint2(q.x, (unsigned)__float_as_uint(dinv[s] * dinv[d]));
            }
        }
        __syncthreads();
    }
}

// ---------------- MFMA GEMM (swapped operands): C^T = W^T @ A^T ----------------
// bf16 hi/lo input version (layers 2,3, lin1).

__global__ __launch_bounds__(256) void gemm_mfma(
    const bf16* __restrict__ ahi, const bf16* __restrict__ alo,
    const float* __restrict__ W, const float* __restrict__ bias,
    bf16* __restrict__ ohi, bf16* __restrict__ olo, int n_rows, int relu_out)
{
    const int lane = threadIdx.x & 63;
    const int wv   = threadIdx.x >> 6;
    const int col0 = wv * 32;
    const int l15  = lane & 15;
    const int lg   = lane >> 4;

    bf16x8 whi[2][4], wlo[2][4];
    #pragma unroll
    for (int t = 0; t < 2; t++) {
        int c = col0 + 16 * t + l15;
        #pragma unroll
        for (int ks = 0; ks < 4; ks++) {
            #pragma unroll
            for (int j = 0; j < 8; j++) {
                float wvv = W[(ks * 32 + lg * 8 + j) * 128 + c];
                bf16 h = (bf16)wvv;
                whi[t][ks][j] = h;
                wlo[t][ks][j] = (bf16)(wvv - (float)h);
            }
        }
    }

    const int nrt = n_rows >> 4;
    for (int rt = blockIdx.x; rt < nrt; rt += gridDim.x) {
        const int row = rt * 16 + l15;
        const bf16* pah = ahi + (size_t)row * 128 + lg * 8;
        const bf16* pal = alo + (size_t)row * 128 + lg * 8;
        bf16x8 Ah[4], Al[4];
        #pragma unroll
        for (int ks = 0; ks < 4; ks++) {
            Ah[ks] = *(const bf16x8*)(pah + ks * 32);
            Al[ks] = *(const bf16x8*)(pal + ks * 32);
        }
        #pragma unroll
        for (int t = 0; t < 2; t++) {
            f32x4 acc = {0.f, 0.f, 0.f, 0.f};
            #pragma unroll
            for (int ks = 0; ks < 4; ks++) {
                acc = __builtin_amdgcn_mfma_f32_16x16x32_bf16(whi[t][ks], Al[ks], acc, 0, 0, 0);
                acc = __builtin_amdgcn_mfma_f32_16x16x32_bf16(wlo[t][ks], Ah[ks], acc, 0, 0, 0);
                acc = __builtin_amdgcn_mfma_f32_16x16x32_bf16(whi[t][ks], Ah[ks], acc, 0, 0, 0);
            }
            const int c0 = col0 + 16 * t + lg * 4;
            f32x4 bv = {0.f, 0.f, 0.f, 0.f};
            if (bias) bv = *(const f32x4*)(bias + c0);
            bf16x4 h, l;
            #pragma unroll
            for (int r = 0; r < 4; r++) {
                float v = acc[r] + bv[r];
                if (relu_out) v = fmaxf(v, 0.f);
                h[r] = (bf16)v;
                l[r] = (bf16)(v - (float)h[r]);
            }
            size_t base = (size_t)(rt * 16 + l15) * 128 + c0;
            *(bf16x4*)(ohi + base) = h;
            *(bf16x4*)(olo + base) = l;
        }
    }
}

// ---------------- MFMA GEMM, fp32 input (layer 1): split x in-register ----------------

__global__ __launch_bounds__(256) void gemm_mfma_x(
    const float* __restrict__ X, const float* __restrict__ W,
    bf16* __restrict__ ohi, bf16* __restrict__ olo, int n_rows)
{
    const int lane = threadIdx.x & 63;
    const int wv   = threadIdx.x >> 6;
    const int col0 = wv * 32;
    const int l15  = lane & 15;
    const int lg   = lane >> 4;

    bf16x8 whi[2][4], wlo[2][4];
    #pragma unroll
    for (int t = 0; t < 2; t++) {
        int c = col0 + 16 * t + l15;
        #pragma unroll
        for (int ks = 0; ks < 4; ks++) {
            #pragma unroll
            for (int j = 0; j < 8; j++) {
                float wvv = W[(ks * 32 + lg * 8 + j) * 128 + c];
                bf16 h = (bf16)wvv;
                whi[t][ks][j] = h;
                wlo[t][ks][j] = (bf16)(wvv - (float)h);
            }
        }
    }

    const int nrt = n_rows >> 4;
    for (int rt = blockIdx.x; rt < nrt; rt += gridDim.x) {
        const int row = rt * 16 + l15;
        const float* px = X + (size_t)row * 128 + lg * 8;
        bf16x8 Ah[4], Al[4];
        #pragma unroll
        for (int ks = 0; ks < 4; ks++) {
            float4 v0 = *(const float4*)(px + ks * 32);
            float4 v1 = *(const float4*)(px + ks * 32 + 4);
            float vv[8] = {v0.x, v0.y, v0.z, v0.w, v1.x, v1.y, v1.z, v1.w};
            #pragma unroll
            for (int j = 0; j < 8; j++) {
                bf16 h = (bf16)vv[j];
                Ah[ks][j] = h;
                Al[ks][j] = (bf16)(vv[j] - (float)h);
            }
        }
        #pragma unroll
        for (int t = 0; t < 2; t++) {
            f32x4 acc = {0.f, 0.f, 0.f, 0.f};
            #pragma unroll
            for (int ks = 0; ks < 4; ks++) {
                acc = __builtin_amdgcn_mfma_f32_16x16x32_bf16(whi[t][ks], Al[ks], acc, 0, 0, 0);
                acc = __builtin_amdgcn_mfma_f32_16x16x32_bf16(wlo[t][ks], Ah[ks], acc, 0, 0, 0);
                acc = __builtin_amdgcn_mfma_f32_16x16x32_bf16(whi[t][ks], Ah[ks], acc, 0, 0, 0);
            }
            const int c0 = col0 + 16 * t + lg * 4;
            bf16x4 h, l;
            #pragma unroll
            for (int r = 0; r < 4; r++) {
                float v = acc[r];
                h[r] = (bf16)v;
                l[r] = (bf16)(v - (float)h[r]);
            }
            size_t base = (size_t)(rt * 16 + l15) * 128 + c0;
            *(bf16x4*)(ohi + base) = h;
            *(bf16x4*)(olo + base) = l;
        }
    }
}

// ---------------- CSR gather aggregation: 2 interleaved edge streams per wave ----------------
// Wave handles nodes 2p and 2p+1 SEQUENTIALLY-ACCUMULATED but with interleaved edge
// loops: per iteration 4 records + 4 full-wave row loads from EACH stream -> 8
// independent row loads in flight from 2 chains (vs 8 from 1 serial chain).
// All 64 lanes stay on one row per load (R14 lesson: never split the wave).

__global__ __launch_bounds__(256) void gather_agg_split(
    const bf16* __restrict__ hhi, const bf16* __restrict__ hlo,
    const uint2* __restrict__ erec, const int* __restrict__ off,
    const float* __restrict__ dinv, const float* __restrict__ bias,
    bf16* __restrict__ ohi, bf16* __restrict__ olo, int n)
{
    int lane = threadIdx.x & 63;
    int wid  = (blockIdx.x * 256 + threadIdx.x) >> 6;
    int nw   = (gridDim.x * 256) >> 6;

    const int f = 2 * lane;
    float bb0 = bias[f], bb1 = bias[f + 1];

    const int npairs = (n + 1) >> 1;
    for (int pair = wid; pair < npairs; pair += nw) {
        const int nodeA = pair * 2;
        const bool hasB = nodeA + 1 < n;
        const int nodeB = hasB ? nodeA + 1 : nodeA;

        // self terms
        float snA = dinv[nodeA]; snA *= snA;
        size_t nbA = (size_t)nodeA * 128 + f;
        bf16x2 shA = *(const bf16x2*)(hhi + nbA);
        bf16x2 slA = *(const bf16x2*)(hlo + nbA);
        float aA0 = fmaf((float)shA[0] + (float)slA[0], snA, bb0);
        float aA1 = fmaf((float)shA[1] + (float)slA[1], snA, bb1);

        float snB = dinv[nodeB]; snB *= snB;
        size_t nbB = (size_t)nodeB * 128 + f;
        bf16x2 shB = *(const bf16x2*)(hhi + nbB);
        bf16x2 slB = *(const bf16x2*)(hlo + nbB);
        float aB0 = fmaf((float)shB[0] + (float)slB[0], snB, bb0);
        float aB1 = fmaf((float)shB[1] + (float)slB[1], snB, bb1);

        int eA = off[nodeA];
        const int eAe = off[nodeA + 1];
        int eB  = hasB ? off[nodeB] : 0;
        const int eBe = hasB ? off[nodeB + 1] : 0;

        // interleaved phase: 4 edges from each stream per iteration
        while (eA + 4 <= eAe && eB + 4 <= eBe) {
            uint2 qa[4], qb[4];
            #pragma unroll
            for (int j = 0; j < 4; j++) { qa[j] = erec[eA + j]; qb[j] = erec[eB + j]; }
            bf16x2 ra[4], rb[4];
            #pragma unroll
            for (int j = 0; j < 4; j++) {
                ra[j] = *(const bf16x2*)(hhi + (size_t)qa[j].x * 128 + f);
                rb[j] = *(const bf16x2*)(hhi + (size_t)qb[j].x * 128 + f);
            }
            #pragma unroll
            for (int j = 0; j < 4; j++) {
                float wa = __uint_as_float(qa[j].y);
                float wb = __uint_as_float(qb[j].y);
                aA0 = fmaf((float)ra[j][0], wa, aA0);
                aA1 = fmaf((float)ra[j][1], wa, aA1);
                aB0 = fmaf((float)rb[j][0], wb, aB0);
                aB1 = fmaf((float)rb[j][1], wb, aB1);
            }
            eA += 4; eB += 4;
        }
        // drain A
        for (; eA + 4 <= eAe; eA += 4) {
            uint2 q[4];
            #pragma unroll
            for (int j = 0; j < 4; j++) q[j] = erec[eA + j];
            bf16x2 r[4];
            #pragma unroll
            for (int j = 0; j < 4; j++)
                r[j] = *(const bf16x2*)(hhi + (size_t)q[j].x * 128 + f);
            #pragma unroll
            for (int j = 0; j < 4; j++) {
                float w = __uint_as_float(q[j].y);
                aA0 = fmaf((float)r[j][0], w, aA0);
                aA1 = fmaf((float)r[j][1], w, aA1);
            }
        }
        for (; eA < eAe; eA++) {
            uint2 q = erec[eA];
            float w = __uint_as_float(q.y);
            bf16x2 r = *(const bf16x2*)(hhi + (size_t)q.x * 128 + f);
            aA0 = fmaf((float)r[0], w, aA0);
            aA1 = fmaf((float)r[1], w, aA1);
        }
        // drain B
        for (; eB + 4 <= eBe; eB += 4) {
            uint2 q[4];
            #pragma unroll
            for (int j = 0; j < 4; j++) q[j] = erec[eB + j];
            bf16x2 r[4];
            #pragma unroll
            for (int j = 0; j < 4; j++)
                r[j] = *(const bf16x2*)(hhi + (size_t)q[j].x * 128 + f);
            #pragma unroll
            for (int j = 0; j < 4; j++) {
                float w = __uint_as_float(q[j].y);
                aB0 = fmaf((float)r[j][0], w, aB0);
                aB1 = fmaf((float)r[j][1], w, aB1);
            }
        }
        for (; eB < eBe; eB++) {
            uint2 q = erec[eB];
            float w = __uint_as_float(q.y);
            bf16x2 r = *(const bf16x2*)(hhi + (size_t)q.x * 128 + f);
            aB0 = fmaf((float)r[0], w, aB0);
            aB1 = fmaf((float)r[1], w, aB1);
        }

        aA0 = fmaxf(aA0, 0.f); aA1 = fmaxf(aA1, 0.f);
        bf16x2 oh, ol;
        oh[0] = (bf16)aA0; ol[0] = (bf16)(aA0 - (float)oh[0]);
        oh[1] = (bf16)aA1; ol[1] = (bf16)(aA1 - (float)oh[1]);
        *(bf16x2*)(ohi + nbA) = oh;
        *(bf16x2*)(olo + nbA) = ol;

        if (hasB) {
            aB0 = fmaxf(aB0, 0.f); aB1 = fmaxf(aB1, 0.f);
            bf16x2 ohB, olB;
            ohB[0] = (bf16)aB0; olB[0] = (bf16)(aB0 - (float)ohB[0]);
            ohB[1] = (bf16)aB1; olB[1] = (bf16)(aB1 - (float)ohB[1]);
            *(bf16x2*)(ohi + nbB) = ohB;
            *(bf16x2*)(olo + nbB) = olB;
        }
    }
}

// ---------------- lin2 + log_softmax via MFMA (swapped operands) ----------------

__global__ __launch_bounds__(256) void lin2_mfma_lsm(
    const bf16* __restrict__ hhi, const bf16* __restrict__ hlo,
    const float* __restrict__ W, const float* __restrict__ bias,
    float* __restrict__ out, int n)
{
    const int lane = threadIdx.x & 63;
    const int l15  = lane & 15;
    const int lg   = lane >> 4;

    bf16x8 whi[3][4], wlo[3][4];
    #pragma unroll
    for (int t = 0; t < 3; t++) {
        int c = t * 16 + l15;
        bool valid = c < 40;
        #pragma unroll
        for (int ks = 0; ks < 4; ks++) {
            #pragma unroll
            for (int j = 0; j < 8; j++) {
                float wv = valid ? W[(ks * 32 + lg * 8 + j) * 40 + c] : 0.f;
                bf16 h = (bf16)wv;
                whi[t][ks][j] = h;
                wlo[t][ks][j] = (bf16)(wv - (float)h);
            }
        }
    }
    f32x4 bb[3];
    bool vstore[3];
    #pragma unroll
    for (int t = 0; t < 3; t++) {
        int c0 = t * 16 + lg * 4;
        vstore[t] = (c0 < 40);
        if (vstore[t]) bb[t] = *(const f32x4*)(bias + c0);
        else bb[t] = (f32x4){0.f, 0.f, 0.f, 0.f};
    }

    int wtile = (blockIdx.x * 256 + threadIdx.x) >> 6;
    int nwt   = (gridDim.x * 256) >> 6;
    int ntiles = (n + 15) >> 4;

    for (int rt = wtile; rt < ntiles; rt += nwt) {
        int arow = rt * 16 + l15;
        if (arow >= n) arow = n - 1;
        const bf16* pah = hhi + (size_t)arow * 128 + lg * 8;
        const bf16* pal = hlo + (size_t)arow * 128 + lg * 8;
        bf16x8 Ah[4], Al[4];
        #pragma unroll
        for (int ks = 0; ks < 4; ks++) {
            Ah[ks] = *(const bf16x8*)(pah + ks * 32);
            Al[ks] = *(const bf16x8*)(pal + ks * 32);
        }
        f32x4 acc[3];
        #pragma unroll
        for (int t = 0; t < 3; t++) {
            acc[t] = (f32x4){0.f, 0.f, 0.f, 0.f};
            #pragma unroll
            for (int ks = 0; ks < 4; ks++) {
                acc[t] = __builtin_amdgcn_mfma_f32_16x16x32_bf16(whi[t][ks], Al[ks], acc[t], 0, 0, 0);
                acc[t] = __builtin_amdgcn_mfma_f32_16x16x32_bf16(wlo[t][ks], Ah[ks], acc[t], 0, 0, 0);
                acc[t] = __builtin_amdgcn_mfma_f32_16x16x32_bf16(whi[t][ks], Ah[ks], acc[t], 0, 0, 0);
            }
        }
        float m = -INFINITY;
        #pragma unroll
        for (int t = 0; t < 3; t++) {
            if (vstore[t]) {
                #pragma unroll
                for (int r = 0; r < 4; r++) m = fmaxf(m, acc[t][r] + bb[t][r]);
            }
        }
        m = fmaxf(m, __shfl_xor(m, 16, 64));
        m = fmaxf(m, __shfl_xor(m, 32, 64));
        float s = 0.f;
        #pragma unroll
        for (int t = 0; t < 3; t++) {
            if (vstore[t]) {
                #pragma unroll
                for (int r = 0; r < 4; r++) s += __expf(acc[t][r] + bb[t][r] - m);
            }
        }
        s += __shfl_xor(s, 16, 64);
        s += __shfl_xor(s, 32, 64);
        float ls = __logf(s) + m;

        int node = rt * 16 + l15;
        if (node < n) {
            #pragma unroll
            for (int t = 0; t < 3; t++) {
                if (vstore[t]) {
                    f32x4 o;
                    #pragma unroll
                    for (int r = 0; r < 4; r++) o[r] = acc[t][r] + bb[t][r] - ls;
                    *(f32x4*)(out + (size_t)node * 40 + t * 16 + lg * 4) = o;
                }
            }
        }
    }
}

// ---------------- launch ----------------

static inline size_t align256(size_t x) { return (x + 255) & ~(size_t)255; }

extern "C" void kernel_launch(void* const* d_in, const int* in_sizes, int n_in,
                              void* d_out, int out_size, void* d_ws, size_t ws_size,
                              hipStream_t stream)
{
    const float* x   = (const float*)d_in[0];
    const int*   ei  = (const int*)d_in[1];
    const float* W1  = (const float*)d_in[2];  const float* b1  = (const float*)d_in[3];
    const float* W2  = (const float*)d_in[4];  const float* b2  = (const float*)d_in[5];
    const float* W3  = (const float*)d_in[6];  const float* b3  = (const float*)d_in[7];
    const float* l1w = (const float*)d_in[8];  const float* l1b = (const float*)d_in[9];
    const float* l2w = (const float*)d_in[10]; const float* l2b = (const float*)d_in[11];

    const int N = in_sizes[0] / 128;
    const int E = in_sizes[1] / 2;
    const int* src = ei;
    const int* dst = ei + E;

    char* wsb = (char*)d_ws;
    size_t o = 0;
    int*   deg   = (int*)(wsb + o);   o = align256(o + (size_t)N * 4);        // reused as cursor
    int*   off   = (int*)(wsb + o);   o = align256(o + (size_t)(N + 1) * 4);
    int*   bsum  = (int*)(wsb + o);   o = align256(o + (size_t)4096 * 4);
    int*   bcur  = (int*)(wsb + o);   o = align256(o + (size_t)512 * 4);
    uint2* erec  = (uint2*)(wsb + o); o = align256(o + (size_t)E * 8);
    float* dinv  = (float*)(wsb + o); o = align256(o + (size_t)N * 4);
    bf16*  ahi   = (bf16*)(wsb + o);  o = align256(o + (size_t)N * 128 * 2);
    bf16*  alo   = (bf16*)(wsb + o);  o = align256(o + (size_t)N * 128 * 2);
    bf16*  hhi   = (bf16*)(wsb + o);  o = align256(o + (size_t)N * 128 * 2);
    bf16*  hlo   = (bf16*)(wsb + o);  o = align256(o + (size_t)N * 128 * 2);

    uint2* ebuf = (uint2*)hhi;   // dead until gemm1; 12.8MB < 25.6MB region

    float* outp = (float*)d_out;
    const int nb   = (N + SCHUNK - 1) / SCHUNK;
    const int nbk  = (N + 255) >> BSH2;                 // 391 buckets
    const int npart = (E + PCH - 1) / PCH;              // 196 chunks

    // ---- CSR build: count, scan, partition, LDS counting sort ----
    zero_i32<<<(N + 255) / 256, 256, 0, stream>>>(deg, N);
    zero_i32<<<2, 256, 0, stream>>>(bcur, 512);
    count_deg<<<2048, 256, 0, stream>>>(dst, deg, E);
    finalize_dinv<<<(N + 255) / 256, 256, 0, stream>>>(deg, dinv, N);
    scan_p1<<<nb, 256, 0, stream>>>(deg, bsum, N);
    scan_p2<<<1, 64, 0, stream>>>(bsum, off, nb, N);
    scan_p3<<<nb, 256, 0, stream>>>(deg, bsum, off, deg /*cursor*/, N);
    partition_edges<<<npart, 256, 0, stream>>>(src, dst, off, bcur, ebuf, E, N, nbk);
    fill_sort<<<nbk, 256, 0, stream>>>(ebuf, off, dinv, deg /*cursor*/, erec, N, nbk);

    // ---- layer 1: gemm directly from fp32 x (split fused in-register) ----
    gemm_mfma_x<<<1024, 256, 0, stream>>>(x, W1, hhi, hlo, N);
    gather_agg_split<<<4096, 256, 0, stream>>>(hhi, hlo, erec, off, dinv, b1, ahi, alo, N);

    // ---- layer 2 ----
    gemm_mfma<<<1024, 256, 0, stream>>>(ahi, alo, W2, nullptr, hhi, hlo, N, 0);
    gather_agg_split<<<4096, 256, 0, stream>>>(hhi, hlo, erec, off, dinv, b2, ahi, alo, N);

    // ---- layer 3 ----
    gemm_mfma<<<1024, 256, 0, stream>>>(ahi, alo, W3, nullptr, hhi, hlo, N, 0);
    gather_agg_split<<<4096, 256, 0, stream>>>(hhi, hlo, erec, off, dinv, b3, ahi, alo, N);

    // ---- lin1 (+bias+relu) -> split bf16 ----
    gemm_mfma<<<1024, 256, 0, stream>>>(ahi, alo, l1w, l1b, hhi, hlo, N, 1);

    // ---- lin2 + log_softmax (MFMA, swapped) ----
    lin2_mfma_lsm<<<512, 256, 0, stream>>>(hhi, hlo, l2w, l2b, outp, N);
}

// Round 17
// 483.819 us; speedup vs baseline: 1.0439x; 1.0439x over previous
//
#include <hip/hip_runtime.h>
#include <math.h>

typedef __bf16 bf16;
typedef bf16  bf16x8 __attribute__((ext_vector_type(8)));
typedef bf16  bf16x4 __attribute__((ext_vector_type(4)));
typedef bf16  bf16x2 __attribute__((ext_vector_type(2)));
typedef float f32x4  __attribute__((ext_vector_type(4)));

#define BSH2 8        // bucket = 256 nodes
#define PCH  8192     // edges per partition chunk
#define CAP  4608     // LDS record capacity per bucket (mean 4096, 8 sigma margin)

// ---------------- degree / norm precompute ----------------

__global__ void zero_i32(int* __restrict__ p, int n) {
    int i = blockIdx.x * blockDim.x + threadIdx.x;
    if (i < n) p[i] = 0;
}

__global__ void count_deg(const int* __restrict__ dst, int* __restrict__ deg, int E) {
    int i = blockIdx.x * blockDim.x + threadIdx.x;
    int stride = gridDim.x * blockDim.x;
    for (; i < E; i += stride) atomicAdd(&deg[dst[i]], 1);
}

__global__ void finalize_dinv(const int* __restrict__ deg, float* __restrict__ dinv, int n) {
    int i = blockIdx.x * blockDim.x + threadIdx.x;
    if (i < n) dinv[i] = rsqrtf((float)deg[i] + 1.0f);   // +1 self-loop
}

// ---------------- parallel 3-phase exclusive scan (node offsets) ----------------
#define SCHUNK 2048

__global__ __launch_bounds__(256) void scan_p1(const int* __restrict__ deg,
                                               int* __restrict__ bsum, int n) {
    int base = blockIdx.x * SCHUNK;
    int s = 0;
    for (int i = threadIdx.x; i < SCHUNK; i += 256) {
        int idx = base + i;
        s += (idx < n) ? deg[idx] : 0;
    }
    #pragma unroll
    for (int o = 32; o >= 1; o >>= 1) s += __shfl_xor(s, o, 64);
    __shared__ int ws[4];
    if ((threadIdx.x & 63) == 0) ws[threadIdx.x >> 6] = s;
    __syncthreads();
    if (threadIdx.x == 0) bsum[blockIdx.x] = ws[0] + ws[1] + ws[2] + ws[3];
}

__global__ __launch_bounds__(64) void scan_p2(int* __restrict__ bsum,
                                              int* __restrict__ off, int nb, int n) {
    int lane = threadIdx.x;
    __shared__ int carry_s;
    if (lane == 0) carry_s = 0;
    __syncthreads();
    for (int base = 0; base < nb; base += 64) {
        int i = base + lane;
        int v = (i < nb) ? bsum[i] : 0;
        int x = v;
        #pragma unroll
        for (int o = 1; o < 64; o <<= 1) {
            int t = __shfl_up(x, o, 64);
            if (lane >= o) x += t;
        }
        int carry = carry_s;
        if (i < nb) bsum[i] = carry + x - v;   // exclusive
        int total = __shfl(x, 63, 64);
        __syncthreads();
        if (lane == 0) carry_s = carry + total;
        __syncthreads();
    }
    if (lane == 0) off[n] = carry_s;
}

__global__ __launch_bounds__(256) void scan_p3(const int* __restrict__ deg,
                                               const int* __restrict__ bsum,
                                               int* __restrict__ off,
                                               int* __restrict__ cursor, int n) {
    int base = blockIdx.x * SCHUNK + (int)threadIdx.x * 8;
    int v[8]; int s = 0;
    #pragma unroll
    for (int j = 0; j < 8; j++) {
        int idx = base + j;
        v[j] = (idx < n) ? deg[idx] : 0;
        s += v[j];
    }
    int lane = threadIdx.x & 63, wv = threadIdx.x >> 6;
    int x = s;
    #pragma unroll
    for (int o = 1; o < 64; o <<= 1) {
        int t = __shfl_up(x, o, 64);
        if (lane >= o) x += t;
    }
    __shared__ int wsum[4];
    if (lane == 63) wsum[wv] = x;
    __syncthreads();
    int wbase = 0;
    #pragma unroll
    for (int w = 0; w < 4; w++) if (w < wv) wbase += wsum[w];
    int tbase = bsum[blockIdx.x] + wbase + x - s;   // exclusive prefix for this thread
    #pragma unroll
    for (int j = 0; j < 8; j++) {
        int idx = base + j;
        if (idx < n) { off[idx] = tbase; cursor[idx] = 0; tbase += v[j]; }
    }
}

// ---------------- pass 1: partition edges by dst bucket (dst>>8), coalesced runs ----------------

__global__ __launch_bounds__(256) void partition_edges(
    const int* __restrict__ src, const int* __restrict__ dst,
    const int* __restrict__ off, int* __restrict__ bcur,
    uint2* __restrict__ ebuf, int E, int n, int nbk)
{
    __shared__ int lhist[512];
    __shared__ int lbase[512];
    __shared__ int lcur[512];
    __shared__ int gbase[512];
    __shared__ int csum[8];
    __shared__ unsigned short stage[PCH];   // 16 KB

    const int tid = threadIdx.x, lane = tid & 63, wv = tid >> 6;

    for (int base = blockIdx.x * PCH; base < E; base += gridDim.x * PCH) {
        const int cnt = min(PCH, E - base);

        for (int b = tid; b < 512; b += 256) lhist[b] = 0;
        __syncthreads();
        for (int i = tid; i < cnt; i += 256)
            atomicAdd(&lhist[dst[base + i] >> BSH2], 1);
        __syncthreads();
        for (int c = wv; c < 8; c += 4) {
            int idx = c * 64 + lane;
            int v = lhist[idx], x = v;
            #pragma unroll
            for (int o = 1; o < 64; o <<= 1) {
                int t = __shfl_up(x, o, 64);
                if (lane >= o) x += t;
            }
            lbase[idx] = x - v;
            if (lane == 63) csum[c] = x;
        }
        __syncthreads();
        if (tid == 0) {
            int acc = 0;
            #pragma unroll
            for (int c = 0; c < 8; c++) { int t = csum[c]; csum[c] = acc; acc += t; }
        }
        __syncthreads();
        for (int c = wv; c < 8; c += 4) {
            int idx = c * 64 + lane;
            lbase[idx] += csum[c];
            lcur[idx] = lbase[idx];
        }
        __syncthreads();
        for (int i = tid; i < cnt; i += 256) {
            int b = dst[base + i] >> BSH2;
            int p = atomicAdd(&lcur[b], 1);
            stage[p] = (unsigned short)i;
        }
        __syncthreads();
        for (int b = tid; b < nbk; b += 256) {
            int cb = lbase[b + 1] - lbase[b];
            if (cb > 0) gbase[b] = off[b << BSH2] + atomicAdd(&bcur[b], cb);
        }
        __syncthreads();
        for (int k = tid; k < cnt; k += 256) {
            int i = base + (int)stage[k];
            int s = src[i], d = dst[i];
            int b = d >> BSH2;
            ebuf[gbase[b] + (k - lbase[b])] = make_uint2((unsigned)s, (unsigned)d);
        }
        __syncthreads();
    }
}

// ---------------- pass 2: per-bucket LDS counting sort -> coalesced erec write ----------------

__global__ __launch_bounds__(256) void fill_sort(
    const uint2* __restrict__ ebuf, const int* __restrict__ off,
    const float* __restrict__ dinv, int* __restrict__ gcur,
    uint2* __restrict__ erec, int n, int nbk)
{
    __shared__ int  lcur[256];
    __shared__ uint2 lrec[CAP];   // 36 KB

    for (int b = blockIdx.x; b < nbk; b += gridDim.x) {
        const int n0 = b << BSH2;
        const int n1 = min(n0 + 256, n);
        const int e0 = off[n0], e1 = off[n1];
        const int cnt = e1 - e0;
        if (threadIdx.x < (unsigned)(n1 - n0))
            lcur[threadIdx.x] = off[n0 + threadIdx.x] - e0;
        __syncthreads();
        if (cnt <= CAP) {
            for (int i = threadIdx.x; i < cnt; i += 256) {
                uint2 q = ebuf[e0 + i];
                int s = (int)q.x, d = (int)q.y;
                int p = atomicAdd(&lcur[d - n0], 1);
                lrec[p] = make_uint2(q.x, (unsigned)__float_as_uint(dinv[s] * dinv[d]));
            }
            __syncthreads();
            for (int i = threadIdx.x; i < cnt; i += 256)
                erec[e0 + i] = lrec[i];
        } else {
            for (int i = threadIdx.x; i < cnt; i += 256) {
                uint2 q = ebuf[e0 + i];
                int s = (int)q.x, d = (int)q.y;
                int p = off[d] + atomicAdd(&gcur[d], 1);
                erec[p] = make_uint2(q.x, (unsigned)__float_as_uint(dinv[s] * dinv[d]));
            }
        }
        __syncthreads();
    }
}

// ---------------- MFMA GEMM (swapped operands): C^T = W^T @ A^T ----------------
// bf16 hi/lo input. Writes hi always; lo only if olo != nullptr (conv layers are
// hi-only: lo was consumed solely by the gather self-term, same rounding scale
// as the hi-only messages).

__global__ __launch_bounds__(256) void gemm_mfma(
    const bf16* __restrict__ ahi, const bf16* __restrict__ alo,
    const float* __restrict__ W, const float* __restrict__ bias,
    bf16* __restrict__ ohi, bf16* __restrict__ olo, int n_rows, int relu_out)
{
    const int lane = threadIdx.x & 63;
    const int wv   = threadIdx.x >> 6;
    const int col0 = wv * 32;
    const int l15  = lane & 15;
    const int lg   = lane >> 4;

    bf16x8 whi[2][4], wlo[2][4];
    #pragma unroll
    for (int t = 0; t < 2; t++) {
        int c = col0 + 16 * t + l15;
        #pragma unroll
        for (int ks = 0; ks < 4; ks++) {
            #pragma unroll
            for (int j = 0; j < 8; j++) {
                float wvv = W[(ks * 32 + lg * 8 + j) * 128 + c];
                bf16 h = (bf16)wvv;
                whi[t][ks][j] = h;
                wlo[t][ks][j] = (bf16)(wvv - (float)h);
            }
        }
    }

    const int nrt = n_rows >> 4;
    for (int rt = blockIdx.x; rt < nrt; rt += gridDim.x) {
        const int row = rt * 16 + l15;
        const bf16* pah = ahi + (size_t)row * 128 + lg * 8;
        const bf16* pal = alo + (size_t)row * 128 + lg * 8;
        bf16x8 Ah[4], Al[4];
        #pragma unroll
        for (int ks = 0; ks < 4; ks++) {
            Ah[ks] = *(const bf16x8*)(pah + ks * 32);
            Al[ks] = *(const bf16x8*)(pal + ks * 32);
        }
        #pragma unroll
        for (int t = 0; t < 2; t++) {
            f32x4 acc = {0.f, 0.f, 0.f, 0.f};
            #pragma unroll
            for (int ks = 0; ks < 4; ks++) {
                acc = __builtin_amdgcn_mfma_f32_16x16x32_bf16(whi[t][ks], Al[ks], acc, 0, 0, 0);
                acc = __builtin_amdgcn_mfma_f32_16x16x32_bf16(wlo[t][ks], Ah[ks], acc, 0, 0, 0);
                acc = __builtin_amdgcn_mfma_f32_16x16x32_bf16(whi[t][ks], Ah[ks], acc, 0, 0, 0);
            }
            const int c0 = col0 + 16 * t + lg * 4;
            f32x4 bv = {0.f, 0.f, 0.f, 0.f};
            if (bias) bv = *(const f32x4*)(bias + c0);
            bf16x4 h, l;
            #pragma unroll
            for (int r = 0; r < 4; r++) {
                float v = acc[r] + bv[r];
                if (relu_out) v = fmaxf(v, 0.f);
                h[r] = (bf16)v;
                l[r] = (bf16)(v - (float)h[r]);
            }
            size_t base = (size_t)(rt * 16 + l15) * 128 + c0;
            *(bf16x4*)(ohi + base) = h;
            if (olo) *(bf16x4*)(olo + base) = l;
        }
    }
}

// ---------------- MFMA GEMM, fp32 input (layer 1): split x in-register, hi-only out ----------------

__global__ __launch_bounds__(256) void gemm_mfma_x(
    const float* __restrict__ X, const float* __restrict__ W,
    bf16* __restrict__ ohi, int n_rows)
{
    const int lane = threadIdx.x & 63;
    const int wv   = threadIdx.x >> 6;
    const int col0 = wv * 32;
    const int l15  = lane & 15;
    const int lg   = lane >> 4;

    bf16x8 whi[2][4], wlo[2][4];
    #pragma unroll
    for (int t = 0; t < 2; t++) {
        int c = col0 + 16 * t + l15;
        #pragma unroll
        for (int ks = 0; ks < 4; ks++) {
            #pragma unroll
            for (int j = 0; j < 8; j++) {
                float wvv = W[(ks * 32 + lg * 8 + j) * 128 + c];
                bf16 h = (bf16)wvv;
                whi[t][ks][j] = h;
                wlo[t][ks][j] = (bf16)(wvv - (float)h);
            }
        }
    }

    const int nrt = n_rows >> 4;
    for (int rt = blockIdx.x; rt < nrt; rt += gridDim.x) {
        const int row = rt * 16 + l15;
        const float* px = X + (size_t)row * 128 + lg * 8;
        bf16x8 Ah[4], Al[4];
        #pragma unroll
        for (int ks = 0; ks < 4; ks++) {
            float4 v0 = *(const float4*)(px + ks * 32);
            float4 v1 = *(const float4*)(px + ks * 32 + 4);
            float vv[8] = {v0.x, v0.y, v0.z, v0.w, v1.x, v1.y, v1.z, v1.w};
            #pragma unroll
            for (int j = 0; j < 8; j++) {
                bf16 h = (bf16)vv[j];
                Ah[ks][j] = h;
                Al[ks][j] = (bf16)(vv[j] - (float)h);
            }
        }
        #pragma unroll
        for (int t = 0; t < 2; t++) {
            f32x4 acc = {0.f, 0.f, 0.f, 0.f};
            #pragma unroll
            for (int ks = 0; ks < 4; ks++) {
                acc = __builtin_amdgcn_mfma_f32_16x16x32_bf16(whi[t][ks], Al[ks], acc, 0, 0, 0);
                acc = __builtin_amdgcn_mfma_f32_16x16x32_bf16(wlo[t][ks], Ah[ks], acc, 0, 0, 0);
                acc = __builtin_amdgcn_mfma_f32_16x16x32_bf16(whi[t][ks], Ah[ks], acc, 0, 0, 0);
            }
            const int c0 = col0 + 16 * t + lg * 4;
            bf16x4 h;
            #pragma unroll
            for (int r = 0; r < 4; r++) h[r] = (bf16)acc[r];
            size_t base = (size_t)(rt * 16 + l15) * 128 + c0;
            *(bf16x4*)(ohi + base) = h;
        }
    }
}

// ---------------- CSR gather aggregation (hi-only hidden state) ----------------
// 1 node/wave, lane covers feats {2l,2l+1}, 8/4/1 edge unroll. Self term hi-only.
// Output: hi+lo split (next gemm's 3-term input precision).

__global__ __launch_bounds__(256) void gather_agg_split(
    const bf16* __restrict__ hhi,
    const uint2* __restrict__ erec, const int* __restrict__ off,
    const float* __restrict__ dinv, const float* __restrict__ bias,
    bf16* __restrict__ ohi, bf16* __restrict__ olo, int n)
{
    int lane = threadIdx.x & 63;
    int wid  = (blockIdx.x * 256 + threadIdx.x) >> 6;
    int nw   = (gridDim.x * 256) >> 6;

    const int f = 2 * lane;
    float bb0 = bias[f], bb1 = bias[f + 1];

    for (int node = wid; node < n; node += nw) {
        float sn = dinv[node]; sn *= sn;
        size_t nb = (size_t)node * 128 + f;
        bf16x2 sh = *(const bf16x2*)(hhi + nb);
        float a0 = fmaf((float)sh[0], sn, bb0);
        float a1 = fmaf((float)sh[1], sn, bb1);

        int e0 = off[node], e1 = off[node + 1];
        int e = e0;
        for (; e + 8 <= e1; e += 8) {
            uint2 q[8];
            #pragma unroll
            for (int j = 0; j < 8; j++) q[j] = erec[e + j];
            bf16x2 r[8];
            #pragma unroll
            for (int j = 0; j < 8; j++)
                r[j] = *(const bf16x2*)(hhi + (size_t)q[j].x * 128 + f);
            #pragma unroll
            for (int j = 0; j < 8; j++) {
                float w = __uint_as_float(q[j].y);
                a0 = fmaf((float)r[j][0], w, a0);
                a1 = fmaf((float)r[j][1], w, a1);
            }
        }
        for (; e + 4 <= e1; e += 4) {
            uint2 q[4];
            #pragma unroll
            for (int j = 0; j < 4; j++) q[j] = erec[e + j];
            bf16x2 r[4];
            #pragma unroll
            for (int j = 0; j < 4; j++)
                r[j] = *(const bf16x2*)(hhi + (size_t)q[j].x * 128 + f);
            #pragma unroll
            for (int j = 0; j < 4; j++) {
                float w = __uint_as_float(q[j].y);
                a0 = fmaf((float)r[j][0], w, a0);
                a1 = fmaf((float)r[j][1], w, a1);
            }
        }
        for (; e < e1; e++) {
            uint2 q = erec[e];
            float w = __uint_as_float(q.y);
            bf16x2 r = *(const bf16x2*)(hhi + (size_t)q.x * 128 + f);
            a0 = fmaf((float)r[0], w, a0);
            a1 = fmaf((float)r[1], w, a1);
        }

        a0 = fmaxf(a0, 0.f);
        a1 = fmaxf(a1, 0.f);
        bf16x2 oh, ol;
        oh[0] = (bf16)a0; ol[0] = (bf16)(a0 - (float)oh[0]);
        oh[1] = (bf16)a1; ol[1] = (bf16)(a1 - (float)oh[1]);
        *(bf16x2*)(ohi + nb) = oh;
        *(bf16x2*)(olo + nb) = ol;
    }
}

// ---------------- lin2 + log_softmax via MFMA (swapped operands) ----------------

__global__ __launch_bounds__(256) void lin2_mfma_lsm(
    const bf16* __restrict__ hhi, const bf16* __restrict__ hlo,
    const float* __restrict__ W, const float* __restrict__ bias,
    float* __restrict__ out, int n)
{
    const int lane = threadIdx.x & 63;
    const int l15  = lane & 15;
    const int lg   = lane >> 4;

    bf16x8 whi[3][4], wlo[3][4];
    #pragma unroll
    for (int t = 0; t < 3; t++) {
        int c = t * 16 + l15;
        bool valid = c < 40;
        #pragma unroll
        for (int ks = 0; ks < 4; ks++) {
            #pragma unroll
            for (int j = 0; j < 8; j++) {
                float wv = valid ? W[(ks * 32 + lg * 8 + j) * 40 + c] : 0.f;
                bf16 h = (bf16)wv;
                whi[t][ks][j] = h;
                wlo[t][ks][j] = (bf16)(wv - (float)h);
            }
        }
    }
    f32x4 bb[3];
    bool vstore[3];
    #pragma unroll
    for (int t = 0; t < 3; t++) {
        int c0 = t * 16 + lg * 4;
        vstore[t] = (c0 < 40);
        if (vstore[t]) bb[t] = *(const f32x4*)(bias + c0);
        else bb[t] = (f32x4){0.f, 0.f, 0.f, 0.f};
    }

    int wtile = (blockIdx.x * 256 + threadIdx.x) >> 6;
    int nwt   = (gridDim.x * 256) >> 6;
    int ntiles = (n + 15) >> 4;

    for (int rt = wtile; rt < ntiles; rt += nwt) {
        int arow = rt * 16 + l15;
        if (arow >= n) arow = n - 1;
        const bf16* pah = hhi + (size_t)arow * 128 + lg * 8;
        const bf16* pal = hlo + (size_t)arow * 128 + lg * 8;
        bf16x8 Ah[4], Al[4];
        #pragma unroll
        for (int ks = 0; ks < 4; ks++) {
            Ah[ks] = *(const bf16x8*)(pah + ks * 32);
            Al[ks] = *(const bf16x8*)(pal + ks * 32);
        }
        f32x4 acc[3];
        #pragma unroll
        for (int t = 0; t < 3; t++) {
            acc[t] = (f32x4){0.f, 0.f, 0.f, 0.f};
            #pragma unroll
            for (int ks = 0; ks < 4; ks++) {
                acc[t] = __builtin_amdgcn_mfma_f32_16x16x32_bf16(whi[t][ks], Al[ks], acc[t], 0, 0, 0);
                acc[t] = __builtin_amdgcn_mfma_f32_16x16x32_bf16(wlo[t][ks], Ah[ks], acc[t], 0, 0, 0);
                acc[t] = __builtin_amdgcn_mfma_f32_16x16x32_bf16(whi[t][ks], Ah[ks], acc[t], 0, 0, 0);
            }
        }
        float m = -INFINITY;
        #pragma unroll
        for (int t = 0; t < 3; t++) {
            if (vstore[t]) {
                #pragma unroll
                for (int r = 0; r < 4; r++) m = fmaxf(m, acc[t][r] + bb[t][r]);
            }
        }
        m = fmaxf(m, __shfl_xor(m, 16, 64));
        m = fmaxf(m, __shfl_xor(m, 32, 64));
        float s = 0.f;
        #pragma unroll
        for (int t = 0; t < 3; t++) {
            if (vstore[t]) {
                #pragma unroll
                for (int r = 0; r < 4; r++) s += __expf(acc[t][r] + bb[t][r] - m);
            }
        }
        s += __shfl_xor(s, 16, 64);
        s += __shfl_xor(s, 32, 64);
        float ls = __logf(s) + m;

        int node = rt * 16 + l15;
        if (node < n) {
            #pragma unroll
            for (int t = 0; t < 3; t++) {
                if (vstore[t]) {
                    f32x4 o;
                    #pragma unroll
                    for (int r = 0; r < 4; r++) o[r] = acc[t][r] + bb[t][r] - ls;
                    *(f32x4*)(out + (size_t)node * 40 + t * 16 + lg * 4) = o;
                }
            }
        }
    }
}

// ---------------- launch ----------------

static inline size_t align256(size_t x) { return (x + 255) & ~(size_t)255; }

extern "C" void kernel_launch(void* const* d_in, const int* in_sizes, int n_in,
                              void* d_out, int out_size, void* d_ws, size_t ws_size,
                              hipStream_t stream)
{
    const float* x   = (const float*)d_in[0];
    const int*   ei  = (const int*)d_in[1];
    const float* W1  = (const float*)d_in[2];  const float* b1  = (const float*)d_in[3];
    const float* W2  = (const float*)d_in[4];  const float* b2  = (const float*)d_in[5];
    const float* W3  = (const float*)d_in[6];  const float* b3  = (const float*)d_in[7];
    const float* l1w = (const float*)d_in[8];  const float* l1b = (const float*)d_in[9];
    const float* l2w = (const float*)d_in[10]; const float* l2b = (const float*)d_in[11];

    const int N = in_sizes[0] / 128;
    const int E = in_sizes[1] / 2;
    const int* src = ei;
    const int* dst = ei + E;

    char* wsb = (char*)d_ws;
    size_t o = 0;
    int*   deg   = (int*)(wsb + o);   o = align256(o + (size_t)N * 4);        // reused as cursor
    int*   off   = (int*)(wsb + o);   o = align256(o + (size_t)(N + 1) * 4);
    int*   bsum  = (int*)(wsb + o);   o = align256(o + (size_t)4096 * 4);
    int*   bcur  = (int*)(wsb + o);   o = align256(o + (size_t)512 * 4);
    uint2* erec  = (uint2*)(wsb + o); o = align256(o + (size_t)E * 8);
    float* dinv  = (float*)(wsb + o); o = align256(o + (size_t)N * 4);
    bf16*  ahi   = (bf16*)(wsb + o);  o = align256(o + (size_t)N * 128 * 2);
    bf16*  alo   = (bf16*)(wsb + o);  o = align256(o + (size_t)N * 128 * 2);
    bf16*  hhi   = (bf16*)(wsb + o);  o = align256(o + (size_t)N * 128 * 2);
    bf16*  hlo   = (bf16*)(wsb + o);  o = align256(o + (size_t)N * 128 * 2);

    uint2* ebuf = (uint2*)hhi;   // dead until gemm1; 12.8MB < 25.6MB region

    float* outp = (float*)d_out;
    const int nb   = (N + SCHUNK - 1) / SCHUNK;
    const int nbk  = (N + 255) >> BSH2;                 // 391 buckets
    const int npart = (E + PCH - 1) / PCH;              // 196 chunks

    // ---- CSR build: count, scan, partition, LDS counting sort ----
    zero_i32<<<(N + 255) / 256, 256, 0, stream>>>(deg, N);
    zero_i32<<<2, 256, 0, stream>>>(bcur, 512);
    count_deg<<<2048, 256, 0, stream>>>(dst, deg, E);
    finalize_dinv<<<(N + 255) / 256, 256, 0, stream>>>(deg, dinv, N);
    scan_p1<<<nb, 256, 0, stream>>>(deg, bsum, N);
    scan_p2<<<1, 64, 0, stream>>>(bsum, off, nb, N);
    scan_p3<<<nb, 256, 0, stream>>>(deg, bsum, off, deg /*cursor*/, N);
    partition_edges<<<npart, 256, 0, stream>>>(src, dst, off, bcur, ebuf, E, N, nbk);
    fill_sort<<<nbk, 256, 0, stream>>>(ebuf, off, dinv, deg /*cursor*/, erec, N, nbk);

    // ---- layer 1: gemm directly from fp32 x (hi-only out) ----
    gemm_mfma_x<<<1024, 256, 0, stream>>>(x, W1, hhi, N);
    gather_agg_split<<<4096, 256, 0, stream>>>(hhi, erec, off, dinv, b1, ahi, alo, N);

    // ---- layer 2 (hi-only out) ----
    gemm_mfma<<<1024, 256, 0, stream>>>(ahi, alo, W2, nullptr, hhi, nullptr, N, 0);
    gather_agg_split<<<4096, 256, 0, stream>>>(hhi, erec, off, dinv, b2, ahi, alo, N);

    // ---- layer 3 (hi-only out) ----
    gemm_mfma<<<1024, 256, 0, stream>>>(ahi, alo, W3, nullptr, hhi, nullptr, N, 0);
    gather_agg_split<<<4096, 256, 0, stream>>>(hhi, erec, off, dinv, b3, ahi, alo, N);

    // ---- lin1 (+bias+relu) -> full hi/lo split (lin2 precision) ----
    gemm_mfma<<<1024, 256, 0, stream>>>(ahi, alo, l1w, l1b, hhi, hlo, N, 1);

    // ---- lin2 + log_softmax (MFMA, swapped) ----
    lin2_mfma_lsm<<<512, 256, 0, stream>>>(hhi, hlo, l2w, l2b, outp, N);
}

// Round 18
// 436.041 us; speedup vs baseline: 1.1583x; 1.1096x over previous
//
#include <hip/hip_runtime.h>
#include <math.h>

typedef __bf16 bf16;
typedef bf16  bf16x8 __attribute__((ext_vector_type(8)));
typedef bf16  bf16x4 __attribute__((ext_vector_type(4)));
typedef bf16  bf16x2 __attribute__((ext_vector_type(2)));
typedef float f32x4  __attribute__((ext_vector_type(4)));

#define BSH2 8        // bucket = 256 nodes
#define PCH  4096     // edges per partition chunk (391 blocks)
#define CAP  4608     // LDS record capacity per bucket (mean 4096, 8 sigma margin)

// ---------------- helpers ----------------

__global__ void zero_i32(int* __restrict__ p, int n) {
    int i = blockIdx.x * blockDim.x + threadIdx.x;
    if (i < n) p[i] = 0;
}

// ---------------- bucket histogram of dst>>8 (sequential read, LDS hist) ----------------

__global__ __launch_bounds__(256) void bhist_k(const int* __restrict__ dst,
                                               int* __restrict__ bhist, int E) {
    __shared__ int lh[512];
    for (int b = threadIdx.x; b < 512; b += 256) lh[b] = 0;
    __syncthreads();
    int i = blockIdx.x * 256 + threadIdx.x;
    int stride = gridDim.x * 256;
    for (; i < E; i += stride) atomicAdd(&lh[dst[i] >> BSH2], 1);
    __syncthreads();
    for (int b = threadIdx.x; b < 512; b += 256)
        if (lh[b]) atomicAdd(&bhist[b], lh[b]);
}

// single wave: exclusive scan bhist[512] -> ebase[513]
__global__ __launch_bounds__(64) void bscan512(const int* __restrict__ bhist,
                                               int* __restrict__ ebase) {
    int lane = threadIdx.x;
    __shared__ int carry_s;
    if (lane == 0) carry_s = 0;
    __syncthreads();
    for (int base = 0; base < 512; base += 64) {
        int v = bhist[base + lane];
        int x = v;
        #pragma unroll
        for (int o = 1; o < 64; o <<= 1) {
            int t = __shfl_up(x, o, 64);
            if (lane >= o) x += t;
        }
        int carry = carry_s;
        ebase[base + lane] = carry + x - v;
        int total = __shfl(x, 63, 64);
        __syncthreads();
        if (lane == 0) carry_s = carry + total;
        __syncthreads();
    }
    if (lane == 0) ebase[512] = carry_s;
}

// ---------------- pass 1: partition edges by dst bucket, coalesced runs ----------------

__global__ __launch_bounds__(256) void partition_edges(
    const int* __restrict__ src, const int* __restrict__ dst,
    const int* __restrict__ ebase, int* __restrict__ bcur,
    uint2* __restrict__ ebuf, int E, int nbk)
{
    __shared__ int lhist[512];
    __shared__ int lbase[513];
    __shared__ int lcur[512];
    __shared__ int gbase[512];
    __shared__ int csum[8];
    __shared__ unsigned short stage[PCH];

    const int tid = threadIdx.x, lane = tid & 63, wv = tid >> 6;

    for (int base = blockIdx.x * PCH; base < E; base += gridDim.x * PCH) {
        const int cnt = min(PCH, E - base);

        for (int b = tid; b < 512; b += 256) lhist[b] = 0;
        __syncthreads();
        for (int i = tid; i < cnt; i += 256)
            atomicAdd(&lhist[dst[base + i] >> BSH2], 1);
        __syncthreads();
        for (int c = wv; c < 8; c += 4) {
            int idx = c * 64 + lane;
            int v = lhist[idx], x = v;
            #pragma unroll
            for (int o = 1; o < 64; o <<= 1) {
                int t = __shfl_up(x, o, 64);
                if (lane >= o) x += t;
            }
            lbase[idx] = x - v;
            if (lane == 63) csum[c] = x;
        }
        __syncthreads();
        if (tid == 0) {
            int acc = 0;
            #pragma unroll
            for (int c = 0; c < 8; c++) { int t = csum[c]; csum[c] = acc; acc += t; }
            lbase[512] = acc + 0;   // placeholder; not used
        }
        __syncthreads();
        for (int c = wv; c < 8; c += 4) {
            int idx = c * 64 + lane;
            lbase[idx] += csum[c];
            lcur[idx] = lbase[idx];
        }
        __syncthreads();
        for (int i = tid; i < cnt; i += 256) {
            int b = dst[base + i] >> BSH2;
            int p = atomicAdd(&lcur[b], 1);
            stage[p] = (unsigned short)i;
        }
        __syncthreads();
        for (int b = tid; b < nbk; b += 256) {
            int cb = ((b + 1 < 512) ? ((b + 1 == 512) ? cnt : lcur[b]) : cnt, lcur[b]) - lbase[b];
            cb = lcur[b] - lbase[b];
            if (cb > 0) gbase[b] = ebase[b] + atomicAdd(&bcur[b], cb);
        }
        __syncthreads();
        for (int k = tid; k < cnt; k += 256) {
            int i = base + (int)stage[k];
            int s = src[i], d = dst[i];
            int b = d >> BSH2;
            ebuf[gbase[b] + (k - lbase[b])] = make_uint2((unsigned)s, (unsigned)d);
        }
        __syncthreads();
    }
}

// ---------------- pass 1.5: per-bucket deg count -> off[] and dinv[] ----------------
// Reads the bucket's ebuf run sequentially; LDS-count per-node degree; LDS scan;
// writes node offsets (bucket base + prefix) and dinv. Replaces the global
// random-atomic count_deg + 3 scan kernels.

__global__ __launch_bounds__(256) void bucket_off_dinv(
    const uint2* __restrict__ ebuf, const int* __restrict__ ebase,
    int* __restrict__ off, float* __restrict__ dinv, int n, int nbk)
{
    __shared__ int ldeg[256];
    __shared__ int wsum[4];
    const int tid = threadIdx.x, lane = tid & 63, wv = tid >> 6;

    for (int b = blockIdx.x; b < nbk; b += gridDim.x) {
        const int n0 = b << BSH2;
        const int n1 = min(n0 + 256, n);
        const int e0 = ebase[b], e1 = ebase[b + 1];

        ldeg[tid] = 0;
        __syncthreads();
        for (int i = e0 + tid; i < e1; i += 256)
            atomicAdd(&ldeg[(int)ebuf[i].y - n0], 1);
        __syncthreads();

        int v = ldeg[tid];
        int x = v;
        #pragma unroll
        for (int o = 1; o < 64; o <<= 1) {
            int t = __shfl_up(x, o, 64);
            if (lane >= o) x += t;
        }
        if (lane == 63) wsum[wv] = x;
        __syncthreads();
        int wbase = 0;
        #pragma unroll
        for (int w = 0; w < 4; w++) if (w < wv) wbase += wsum[w];
        int pref = wbase + x - v;   // exclusive prefix

        if (n0 + tid < n1) {
            off[n0 + tid]  = e0 + pref;
            dinv[n0 + tid] = rsqrtf((float)v + 1.0f);
        }
        __syncthreads();
    }
    if (blockIdx.x == 0 && threadIdx.x == 0) off[n] = ebase[nbk];
}

// ---------------- pass 2: per-bucket LDS counting sort -> coalesced erec write ----------------

__global__ __launch_bounds__(256) void fill_sort(
    const uint2* __restrict__ ebuf, const int* __restrict__ off,
    const float* __restrict__ dinv, int* __restrict__ gcur,
    uint2* __restrict__ erec, int n, int nbk)
{
    __shared__ int  lcur[256];
    __shared__ uint2 lrec[CAP];   // 36 KB

    for (int b = blockIdx.x; b < nbk; b += gridDim.x) {
        const int n0 = b << BSH2;
        const int n1 = min(n0 + 256, n);
        const int e0 = off[n0], e1 = off[n1];
        const int cnt = e1 - e0;
        if (threadIdx.x < (unsigned)(n1 - n0))
            lcur[threadIdx.x] = off[n0 + threadIdx.x] - e0;
        __syncthreads();
        if (cnt <= CAP) {
            for (int i = threadIdx.x; i < cnt; i += 256) {
                uint2 q = ebuf[e0 + i];
                int s = (int)q.x, d = (int)q.y;
                int p = atomicAdd(&lcur[d - n0], 1);
                lrec[p] = make_uint2(q.x, (unsigned)__float_as_uint(dinv[s] * dinv[d]));
            }
            __syncthreads();
            for (int i = threadIdx.x; i < cnt; i += 256)
                erec[e0 + i] = lrec[i];
        } else {
            for (int i = threadIdx.x; i < cnt; i += 256) {
                uint2 q = ebuf[e0 + i];
                int s = (int)q.x, d = (int)q.y;
                int p = off[d] + atomicAdd(&gcur[d], 1);
                erec[p] = make_uint2(q.x, (unsigned)__float_as_uint(dinv[s] * dinv[d]));
            }
        }
        __syncthreads();
    }
}

// ---------------- MFMA GEMM (swapped operands): C^T = W^T @ A^T ----------------

__global__ __launch_bounds__(256) void gemm_mfma(
    const bf16* __restrict__ ahi, const bf16* __restrict__ alo,
    const float* __restrict__ W, const float* __restrict__ bias,
    bf16* __restrict__ ohi, bf16* __restrict__ olo, int n_rows, int relu_out)
{
    const int lane = threadIdx.x & 63;
    const int wv   = threadIdx.x >> 6;
    const int col0 = wv * 32;
    const int l15  = lane & 15;
    const int lg   = lane >> 4;

    bf16x8 whi[2][4], wlo[2][4];
    #pragma unroll
    for (int t = 0; t < 2; t++) {
        int c = col0 + 16 * t + l15;
        #pragma unroll
        for (int ks = 0; ks < 4; ks++) {
            #pragma unroll
            for (int j = 0; j < 8; j++) {
                float wvv = W[(ks * 32 + lg * 8 + j) * 128 + c];
                bf16 h = (bf16)wvv;
                whi[t][ks][j] = h;
                wlo[t][ks][j] = (bf16)(wvv - (float)h);
            }
        }
    }

    const int nrt = n_rows >> 4;
    for (int rt = blockIdx.x; rt < nrt; rt += gridDim.x) {
        const int row = rt * 16 + l15;
        const bf16* pah = ahi + (size_t)row * 128 + lg * 8;
        const bf16* pal = alo + (size_t)row * 128 + lg * 8;
        bf16x8 Ah[4], Al[4];
        #pragma unroll
        for (int ks = 0; ks < 4; ks++) {
            Ah[ks] = *(const bf16x8*)(pah + ks * 32);
            Al[ks] = *(const bf16x8*)(pal + ks * 32);
        }
        #pragma unroll
        for (int t = 0; t < 2; t++) {
            f32x4 acc = {0.f, 0.f, 0.f, 0.f};
            #pragma unroll
            for (int ks = 0; ks < 4; ks++) {
                acc = __builtin_amdgcn_mfma_f32_16x16x32_bf16(whi[t][ks], Al[ks], acc, 0, 0, 0);
                acc = __builtin_amdgcn_mfma_f32_16x16x32_bf16(wlo[t][ks], Ah[ks], acc, 0, 0, 0);
                acc = __builtin_amdgcn_mfma_f32_16x16x32_bf16(whi[t][ks], Ah[ks], acc, 0, 0, 0);
            }
            const int c0 = col0 + 16 * t + lg * 4;
            f32x4 bv = {0.f, 0.f, 0.f, 0.f};
            if (bias) bv = *(const f32x4*)(bias + c0);
            bf16x4 h, l;
            #pragma unroll
            for (int r = 0; r < 4; r++) {
                float v = acc[r] + bv[r];
                if (relu_out) v = fmaxf(v, 0.f);
                h[r] = (bf16)v;
                l[r] = (bf16)(v - (float)h[r]);
            }
            size_t base = (size_t)(rt * 16 + l15) * 128 + c0;
            *(bf16x4*)(ohi + base) = h;
            if (olo) *(bf16x4*)(olo + base) = l;
        }
    }
}

// ---------------- MFMA GEMM, fp32 input (layer 1): split x in-register, hi-only out ----------------

__global__ __launch_bounds__(256) void gemm_mfma_x(
    const float* __restrict__ X, const float* __restrict__ W,
    bf16* __restrict__ ohi, int n_rows)
{
    const int lane = threadIdx.x & 63;
    const int wv   = threadIdx.x >> 6;
    const int col0 = wv * 32;
    const int l15  = lane & 15;
    const int lg   = lane >> 4;

    bf16x8 whi[2][4], wlo[2][4];
    #pragma unroll
    for (int t = 0; t < 2; t++) {
        int c = col0 + 16 * t + l15;
        #pragma unroll
        for (int ks = 0; ks < 4; ks++) {
            #pragma unroll
            for (int j = 0; j < 8; j++) {
                float wvv = W[(ks * 32 + lg * 8 + j) * 128 + c];
                bf16 h = (bf16)wvv;
                whi[t][ks][j] = h;
                wlo[t][ks][j] = (bf16)(wvv - (float)h);
            }
        }
    }

    const int nrt = n_rows >> 4;
    for (int rt = blockIdx.x; rt < nrt; rt += gridDim.x) {
        const int row = rt * 16 + l15;
        const float* px = X + (size_t)row * 128 + lg * 8;
        bf16x8 Ah[4], Al[4];
        #pragma unroll
        for (int ks = 0; ks < 4; ks++) {
            float4 v0 = *(const float4*)(px + ks * 32);
            float4 v1 = *(const float4*)(px + ks * 32 + 4);
            float vv[8] = {v0.x, v0.y, v0.z, v0.w, v1.x, v1.y, v1.z, v1.w};
            #pragma unroll
            for (int j = 0; j < 8; j++) {
                bf16 h = (bf16)vv[j];
                Ah[ks][j] = h;
                Al[ks][j] = (bf16)(vv[j] - (float)h);
            }
        }
        #pragma unroll
        for (int t = 0; t < 2; t++) {
            f32x4 acc = {0.f, 0.f, 0.f, 0.f};
            #pragma unroll
            for (int ks = 0; ks < 4; ks++) {
                acc = __builtin_amdgcn_mfma_f32_16x16x32_bf16(whi[t][ks], Al[ks], acc, 0, 0, 0);
                acc = __builtin_amdgcn_mfma_f32_16x16x32_bf16(wlo[t][ks], Ah[ks], acc, 0, 0, 0);
                acc = __builtin_amdgcn_mfma_f32_16x16x32_bf16(whi[t][ks], Ah[ks], acc, 0, 0, 0);
            }
            const int c0 = col0 + 16 * t + lg * 4;
            bf16x4 h;
            #pragma unroll
            for (int r = 0; r < 4; r++) h[r] = (bf16)acc[r];
            size_t base = (size_t)(rt * 16 + l15) * 128 + c0;
            *(bf16x4*)(ohi + base) = h;
        }
    }
}

// ---------------- CSR gather aggregation (hi-only hidden state) ----------------

__global__ __launch_bounds__(256) void gather_agg_split(
    const bf16* __restrict__ hhi,
    const uint2* __restrict__ erec, const int* __restrict__ off,
    const float* __restrict__ dinv, const float* __restrict__ bias,
    bf16* __restrict__ ohi, bf16* __restrict__ olo, int n)
{
    int lane = threadIdx.x & 63;
    int wid  = (blockIdx.x * 256 + threadIdx.x) >> 6;
    int nw   = (gridDim.x * 256) >> 6;

    const int f = 2 * lane;
    float bb0 = bias[f], bb1 = bias[f + 1];

    for (int node = wid; node < n; node += nw) {
        float sn = dinv[node]; sn *= sn;
        size_t nb = (size_t)node * 128 + f;
        bf16x2 sh = *(const bf16x2*)(hhi + nb);
        float a0 = fmaf((float)sh[0], sn, bb0);
        float a1 = fmaf((float)sh[1], sn, bb1);

        int e0 = off[node], e1 = off[node + 1];
        int e = e0;
        for (; e + 8 <= e1; e += 8) {
            uint2 q[8];
            #pragma unroll
            for (int j = 0; j < 8; j++) q[j] = erec[e + j];
            bf16x2 r[8];
            #pragma unroll
            for (int j = 0; j < 8; j++)
                r[j] = *(const bf16x2*)(hhi + (size_t)q[j].x * 128 + f);
            #pragma unroll
            for (int j = 0; j < 8; j++) {
                float w = __uint_as_float(q[j].y);
                a0 = fmaf((float)r[j][0], w, a0);
                a1 = fmaf((float)r[j][1], w, a1);
            }
        }
        for (; e + 4 <= e1; e += 4) {
            uint2 q[4];
            #pragma unroll
            for (int j = 0; j < 4; j++) q[j] = erec[e + j];
            bf16x2 r[4];
            #pragma unroll
            for (int j = 0; j < 4; j++)
                r[j] = *(const bf16x2*)(hhi + (size_t)q[j].x * 128 + f);
            #pragma unroll
            for (int j = 0; j < 4; j++) {
                float w = __uint_as_float(q[j].y);
                a0 = fmaf((float)r[j][0], w, a0);
                a1 = fmaf((float)r[j][1], w, a1);
            }
        }
        for (; e < e1; e++) {
            uint2 q = erec[e];
            float w = __uint_as_float(q.y);
            bf16x2 r = *(const bf16x2*)(hhi + (size_t)q.x * 128 + f);
            a0 = fmaf((float)r[0], w, a0);
            a1 = fmaf((float)r[1], w, a1);
        }

        a0 = fmaxf(a0, 0.f);
        a1 = fmaxf(a1, 0.f);
        bf16x2 oh, ol;
        oh[0] = (bf16)a0; ol[0] = (bf16)(a0 - (float)oh[0]);
        oh[1] = (bf16)a1; ol[1] = (bf16)(a1 - (float)oh[1]);
        *(bf16x2*)(ohi + nb) = oh;
        *(bf16x2*)(olo + nb) = ol;
    }
}

// ---------------- lin2 + log_softmax via MFMA (swapped operands) ----------------

__global__ __launch_bounds__(256) void lin2_mfma_lsm(
    const bf16* __restrict__ hhi, const bf16* __restrict__ hlo,
    const float* __restrict__ W, const float* __restrict__ bias,
    float* __restrict__ out, int n)
{
    const int lane = threadIdx.x & 63;
    const int l15  = lane & 15;
    const int lg   = lane >> 4;

    bf16x8 whi[3][4], wlo[3][4];
    #pragma unroll
    for (int t = 0; t < 3; t++) {
        int c = t * 16 + l15;
        bool valid = c < 40;
        #pragma unroll
        for (int ks = 0; ks < 4; ks++) {
            #pragma unroll
            for (int j = 0; j < 8; j++) {
                float wv = valid ? W[(ks * 32 + lg * 8 + j) * 40 + c] : 0.f;
                bf16 h = (bf16)wv;
                whi[t][ks][j] = h;
                wlo[t][ks][j] = (bf16)(wv - (float)h);
            }
        }
    }
    f32x4 bb[3];
    bool vstore[3];
    #pragma unroll
    for (int t = 0; t < 3; t++) {
        int c0 = t * 16 + lg * 4;
        vstore[t] = (c0 < 40);
        if (vstore[t]) bb[t] = *(const f32x4*)(bias + c0);
        else bb[t] = (f32x4){0.f, 0.f, 0.f, 0.f};
    }

    int wtile = (blockIdx.x * 256 + threadIdx.x) >> 6;
    int nwt   = (gridDim.x * 256) >> 6;
    int ntiles = (n + 15) >> 4;

    for (int rt = wtile; rt < ntiles; rt += nwt) {
        int arow = rt * 16 + l15;
        if (arow >= n) arow = n - 1;
        const bf16* pah = hhi + (size_t)arow * 128 + lg * 8;
        const bf16* pal = hlo + (size_t)arow * 128 + lg * 8;
        bf16x8 Ah[4], Al[4];
        #pragma unroll
        for (int ks = 0; ks < 4; ks++) {
            Ah[ks] = *(const bf16x8*)(pah + ks * 32);
            Al[ks] = *(const bf16x8*)(pal + ks * 32);
        }
        f32x4 acc[3];
        #pragma unroll
        for (int t = 0; t < 3; t++) {
            acc[t] = (f32x4){0.f, 0.f, 0.f, 0.f};
            #pragma unroll
            for (int ks = 0; ks < 4; ks++) {
                acc[t] = __builtin_amdgcn_mfma_f32_16x16x32_bf16(whi[t][ks], Al[ks], acc[t], 0, 0, 0);
                acc[t] = __builtin_amdgcn_mfma_f32_16x16x32_bf16(wlo[t][ks], Ah[ks], acc[t], 0, 0, 0);
                acc[t] = __builtin_amdgcn_mfma_f32_16x16x32_bf16(whi[t][ks], Ah[ks], acc[t], 0, 0, 0);
            }
        }
        float m = -INFINITY;
        #pragma unroll
        for (int t = 0; t < 3; t++) {
            if (vstore[t]) {
                #pragma unroll
                for (int r = 0; r < 4; r++) m = fmaxf(m, acc[t][r] + bb[t][r]);
            }
        }
        m = fmaxf(m, __shfl_xor(m, 16, 64));
        m = fmaxf(m, __shfl_xor(m, 32, 64));
        float s = 0.f;
        #pragma unroll
        for (int t = 0; t < 3; t++) {
            if (vstore[t]) {
                #pragma unroll
                for (int r = 0; r < 4; r++) s += __expf(acc[t][r] + bb[t][r] - m);
            }
        }
        s += __shfl_xor(s, 16, 64);
        s += __shfl_xor(s, 32, 64);
        float ls = __logf(s) + m;

        int node = rt * 16 + l15;
        if (node < n) {
            #pragma unroll
            for (int t = 0; t < 3; t++) {
                if (vstore[t]) {
                    f32x4 o;
                    #pragma unroll
                    for (int r = 0; r < 4; r++) o[r] = acc[t][r] + bb[t][r] - ls;
                    *(f32x4*)(out + (size_t)node * 40 + t * 16 + lg * 4) = o;
                }
            }
        }
    }
}

// ---------------- launch ----------------

static inline size_t align256(size_t x) { return (x + 255) & ~(size_t)255; }

extern "C" void kernel_launch(void* const* d_in, const int* in_sizes, int n_in,
                              void* d_out, int out_size, void* d_ws, size_t ws_size,
                              hipStream_t stream)
{
    const float* x   = (const float*)d_in[0];
    const int*   ei  = (const int*)d_in[1];
    const float* W1  = (const float*)d_in[2];  const float* b1  = (const float*)d_in[3];
    const float* W2  = (const float*)d_in[4];  const float* b2  = (const float*)d_in[5];
    const float* W3  = (const float*)d_in[6];  const float* b3  = (const float*)d_in[7];
    const float* l1w = (const float*)d_in[8];  const float* l1b = (const float*)d_in[9];
    const float* l2w = (const float*)d_in[10]; const float* l2b = (const float*)d_in[11];

    const int N = in_sizes[0] / 128;
    const int E = in_sizes[1] / 2;
    const int* src = ei;
    const int* dst = ei + E;

    char* wsb = (char*)d_ws;
    size_t o = 0;
    int*   gcur  = (int*)(wsb + o);   o = align256(o + (size_t)N * 4);        // fill_sort fallback cursors
    int*   off   = (int*)(wsb + o);   o = align256(o + (size_t)(N + 1) * 4);
    int*   bhist = (int*)(wsb + o);   o = align256(o + (size_t)512 * 4);
    int*   bcur  = (int*)(wsb + o);   o = align256(o + (size_t)512 * 4);
    int*   ebase = (int*)(wsb + o);   o = align256(o + (size_t)513 * 4);
    uint2* erec  = (uint2*)(wsb + o); o = align256(o + (size_t)E * 8);
    float* dinv  = (float*)(wsb + o); o = align256(o + (size_t)N * 4);
    bf16*  ahi   = (bf16*)(wsb + o);  o = align256(o + (size_t)N * 128 * 2);
    bf16*  alo   = (bf16*)(wsb + o);  o = align256(o + (size_t)N * 128 * 2);
    bf16*  hhi   = (bf16*)(wsb + o);  o = align256(o + (size_t)N * 128 * 2);
    bf16*  hlo   = (bf16*)(wsb + o);  o = align256(o + (size_t)N * 128 * 2);

    uint2* ebuf = (uint2*)hhi;   // dead until gemm1; 12.8MB < 25.6MB region

    float* outp = (float*)d_out;
    const int nbk  = (N + 255) >> BSH2;                 // 391 buckets
    const int npart = (E + PCH - 1) / PCH;              // 391 chunks

    // ---- CSR build: bucket hist, scan, partition, per-bucket off/dinv, counting sort ----
    zero_i32<<<(N + 255) / 256, 256, 0, stream>>>(gcur, N);
    zero_i32<<<4, 256, 0, stream>>>(bhist, 1024);       // bhist + bcur (contiguous)
    bhist_k<<<1024, 256, 0, stream>>>(dst, bhist, E);
    bscan512<<<1, 64, 0, stream>>>(bhist, ebase);
    partition_edges<<<npart, 256, 0, stream>>>(src, dst, ebase, bcur, ebuf, E, nbk);
    bucket_off_dinv<<<nbk, 256, 0, stream>>>(ebuf, ebase, off, dinv, N, nbk);
    fill_sort<<<nbk, 256, 0, stream>>>(ebuf, off, dinv, gcur, erec, N, nbk);

    // ---- layer 1: gemm directly from fp32 x (hi-only out) ----
    gemm_mfma_x<<<1024, 256, 0, stream>>>(x, W1, hhi, N);
    gather_agg_split<<<4096, 256, 0, stream>>>(hhi, erec, off, dinv, b1, ahi, alo, N);

    // ---- layer 2 (hi-only out) ----
    gemm_mfma<<<1024, 256, 0, stream>>>(ahi, alo, W2, nullptr, hhi, nullptr, N, 0);
    gather_agg_split<<<4096, 256, 0, stream>>>(hhi, erec, off, dinv, b2, ahi, alo, N);

    // ---- layer 3 (hi-only out) ----
    gemm_mfma<<<1024, 256, 0, stream>>>(ahi, alo, W3, nullptr, hhi, nullptr, N, 0);
    gather_agg_split<<<4096, 256, 0, stream>>>(hhi, erec, off, dinv, b3, ahi, alo, N);

    // ---- lin1 (+bias+relu) -> full hi/lo split (lin2 precision) ----
    gemm_mfma<<<1024, 256, 0, stream>>>(ahi, alo, l1w, l1b, hhi, hlo, N, 1);

    // ---- lin2 + log_softmax (MFMA, swapped) ----
    lin2_mfma_lsm<<<512, 256, 0, stream>>>(hhi, hlo, l2w, l2b, outp, N);
}

// Round 19
// 396.286 us; speedup vs baseline: 1.2745x; 1.1003x over previous
//
#include <hip/hip_runtime.h>
#include <math.h>

typedef __bf16 bf16;
typedef bf16  bf16x8 __attribute__((ext_vector_type(8)));
typedef bf16  bf16x4 __attribute__((ext_vector_type(4)));
typedef bf16  bf16x2 __attribute__((ext_vector_type(2)));
typedef float f32x4  __attribute__((ext_vector_type(4)));

#define BSH2 8        // bucket = 256 nodes
#define PCH  4096     // edges per partition chunk (391 blocks)
#define CAP  4608     // LDS record capacity per bucket (mean 4096, 8 sigma margin)

// ---------------- helpers ----------------

__global__ void zero_i32(int* __restrict__ p, int n) {
    int i = blockIdx.x * blockDim.x + threadIdx.x;
    if (i < n) p[i] = 0;
}

// ---------------- bucket histogram of dst>>8 (sequential read, LDS hist) ----------------

__global__ __launch_bounds__(256) void bhist_k(const int* __restrict__ dst,
                                               int* __restrict__ bhist, int E) {
    __shared__ int lh[512];
    for (int b = threadIdx.x; b < 512; b += 256) lh[b] = 0;
    __syncthreads();
    int i = blockIdx.x * 256 + threadIdx.x;
    int stride = gridDim.x * 256;
    for (; i < E; i += stride) atomicAdd(&lh[dst[i] >> BSH2], 1);
    __syncthreads();
    for (int b = threadIdx.x; b < 512; b += 256)
        if (lh[b]) atomicAdd(&bhist[b], lh[b]);
}

// single wave: exclusive scan bhist[512] -> ebase[513]
__global__ __launch_bounds__(64) void bscan512(const int* __restrict__ bhist,
                                               int* __restrict__ ebase) {
    int lane = threadIdx.x;
    __shared__ int carry_s;
    if (lane == 0) carry_s = 0;
    __syncthreads();
    for (int base = 0; base < 512; base += 64) {
        int v = bhist[base + lane];
        int x = v;
        #pragma unroll
        for (int o = 1; o < 64; o <<= 1) {
            int t = __shfl_up(x, o, 64);
            if (lane >= o) x += t;
        }
        int carry = carry_s;
        ebase[base + lane] = carry + x - v;
        int total = __shfl(x, 63, 64);
        __syncthreads();
        if (lane == 0) carry_s = carry + total;
        __syncthreads();
    }
    if (lane == 0) ebase[512] = carry_s;
}

// ---------------- pass 1: partition edges by dst bucket, coalesced runs ----------------

__global__ __launch_bounds__(256) void partition_edges(
    const int* __restrict__ src, const int* __restrict__ dst,
    const int* __restrict__ ebase, int* __restrict__ bcur,
    uint2* __restrict__ ebuf, int E, int nbk)
{
    __shared__ int lhist[512];
    __shared__ int lbase[512];
    __shared__ int lcur[512];
    __shared__ int gbase[512];
    __shared__ int csum[8];
    __shared__ unsigned short stage[PCH];

    const int tid = threadIdx.x, lane = tid & 63, wv = tid >> 6;

    for (int base = blockIdx.x * PCH; base < E; base += gridDim.x * PCH) {
        const int cnt = min(PCH, E - base);

        for (int b = tid; b < 512; b += 256) lhist[b] = 0;
        __syncthreads();
        for (int i = tid; i < cnt; i += 256)
            atomicAdd(&lhist[dst[base + i] >> BSH2], 1);
        __syncthreads();
        for (int c = wv; c < 8; c += 4) {
            int idx = c * 64 + lane;
            int v = lhist[idx], x = v;
            #pragma unroll
            for (int o = 1; o < 64; o <<= 1) {
                int t = __shfl_up(x, o, 64);
                if (lane >= o) x += t;
            }
            lbase[idx] = x - v;
            if (lane == 63) csum[c] = x;
        }
        __syncthreads();
        if (tid == 0) {
            int acc = 0;
            #pragma unroll
            for (int c = 0; c < 8; c++) { int t = csum[c]; csum[c] = acc; acc += t; }
        }
        __syncthreads();
        for (int c = wv; c < 8; c += 4) {
            int idx = c * 64 + lane;
            lbase[idx] += csum[c];
            lcur[idx] = lbase[idx];
        }
        __syncthreads();
        for (int i = tid; i < cnt; i += 256) {
            int b = dst[base + i] >> BSH2;
            int p = atomicAdd(&lcur[b], 1);
            stage[p] = (unsigned short)i;
        }
        __syncthreads();
        for (int b = tid; b < nbk; b += 256) {
            int cb = lcur[b] - lbase[b];
            if (cb > 0) gbase[b] = ebase[b] + atomicAdd(&bcur[b], cb);
        }
        __syncthreads();
        for (int k = tid; k < cnt; k += 256) {
            int i = base + (int)stage[k];
            int s = src[i], d = dst[i];
            int b = d >> BSH2;
            ebuf[gbase[b] + (k - lbase[b])] = make_uint2((unsigned)s, (unsigned)d);
        }
        __syncthreads();
    }
}

// ---------------- pass 1.5: per-bucket deg count -> off[] and dinv[] ----------------

__global__ __launch_bounds__(256) void bucket_off_dinv(
    const uint2* __restrict__ ebuf, const int* __restrict__ ebase,
    int* __restrict__ off, float* __restrict__ dinv, int n, int nbk)
{
    __shared__ int ldeg[256];
    __shared__ int wsum[4];
    const int tid = threadIdx.x, lane = tid & 63, wv = tid >> 6;

    for (int b = blockIdx.x; b < nbk; b += gridDim.x) {
        const int n0 = b << BSH2;
        const int n1 = min(n0 + 256, n);
        const int e0 = ebase[b], e1 = ebase[b + 1];

        ldeg[tid] = 0;
        __syncthreads();
        for (int i = e0 + tid; i < e1; i += 256)
            atomicAdd(&ldeg[(int)ebuf[i].y - n0], 1);
        __syncthreads();

        int v = ldeg[tid];
        int x = v;
        #pragma unroll
        for (int o = 1; o < 64; o <<= 1) {
            int t = __shfl_up(x, o, 64);
            if (lane >= o) x += t;
        }
        if (lane == 63) wsum[wv] = x;
        __syncthreads();
        int wbase = 0;
        #pragma unroll
        for (int w = 0; w < 4; w++) if (w < wv) wbase += wsum[w];
        int pref = wbase + x - v;   // exclusive prefix

        if (n0 + tid < n1) {
            off[n0 + tid]  = e0 + pref;
            dinv[n0 + tid] = rsqrtf((float)v + 1.0f);
        }
        __syncthreads();
    }
    if (blockIdx.x == 0 && threadIdx.x == 0) off[n] = ebase[nbk];
}

// ---------------- pass 2: per-bucket LDS counting sort -> coalesced erec write ----------------

__global__ __launch_bounds__(256) void fill_sort(
    const uint2* __restrict__ ebuf, const int* __restrict__ off,
    const float* __restrict__ dinv, int* __restrict__ gcur,
    uint2* __restrict__ erec, int n, int nbk)
{
    __shared__ int  lcur[256];
    __shared__ uint2 lrec[CAP];   // 36 KB

    for (int b = blockIdx.x; b < nbk; b += gridDim.x) {
        const int n0 = b << BSH2;
        const int n1 = min(n0 + 256, n);
        const int e0 = off[n0], e1 = off[n1];
        const int cnt = e1 - e0;
        if (threadIdx.x < (unsigned)(n1 - n0))
            lcur[threadIdx.x] = off[n0 + threadIdx.x] - e0;
        __syncthreads();
        if (cnt <= CAP) {
            for (int i = threadIdx.x; i < cnt; i += 256) {
                uint2 q = ebuf[e0 + i];
                int s = (int)q.x, d = (int)q.y;
                int p = atomicAdd(&lcur[d - n0], 1);
                lrec[p] = make_uint2(q.x, (unsigned)__float_as_uint(dinv[s] * dinv[d]));
            }
            __syncthreads();
            for (int i = threadIdx.x; i < cnt; i += 256)
                erec[e0 + i] = lrec[i];
        } else {
            for (int i = threadIdx.x; i < cnt; i += 256) {
                uint2 q = ebuf[e0 + i];
                int s = (int)q.x, d = (int)q.y;
                int p = off[d] + atomicAdd(&gcur[d], 1);
                erec[p] = make_uint2(q.x, (unsigned)__float_as_uint(dinv[s] * dinv[d]));
            }
        }
        __syncthreads();
    }
}

// ---------------- MFMA GEMM (swapped operands), bf16-hi activation input ----------------
// 2-term: C^T = (Whi + Wlo)^T @ Ah^T — W keeps full split precision, activations bf16.
// Writes hi always; lo only if olo != nullptr (lin1 -> lin2 precision).

__global__ __launch_bounds__(256) void gemm_mfma(
    const bf16* __restrict__ ahi,
    const float* __restrict__ W, const float* __restrict__ bias,
    bf16* __restrict__ ohi, bf16* __restrict__ olo, int n_rows, int relu_out)
{
    const int lane = threadIdx.x & 63;
    const int wv   = threadIdx.x >> 6;
    const int col0 = wv * 32;
    const int l15  = lane & 15;
    const int lg   = lane >> 4;

    bf16x8 whi[2][4], wlo[2][4];
    #pragma unroll
    for (int t = 0; t < 2; t++) {
        int c = col0 + 16 * t + l15;
        #pragma unroll
        for (int ks = 0; ks < 4; ks++) {
            #pragma unroll
            for (int j = 0; j < 8; j++) {
                float wvv = W[(ks * 32 + lg * 8 + j) * 128 + c];
                bf16 h = (bf16)wvv;
                whi[t][ks][j] = h;
                wlo[t][ks][j] = (bf16)(wvv - (float)h);
            }
        }
    }

    const int nrt = n_rows >> 4;
    for (int rt = blockIdx.x; rt < nrt; rt += gridDim.x) {
        const int row = rt * 16 + l15;
        const bf16* pah = ahi + (size_t)row * 128 + lg * 8;
        bf16x8 Ah[4];
        #pragma unroll
        for (int ks = 0; ks < 4; ks++)
            Ah[ks] = *(const bf16x8*)(pah + ks * 32);
        #pragma unroll
        for (int t = 0; t < 2; t++) {
            f32x4 acc = {0.f, 0.f, 0.f, 0.f};
            #pragma unroll
            for (int ks = 0; ks < 4; ks++) {
                acc = __builtin_amdgcn_mfma_f32_16x16x32_bf16(wlo[t][ks], Ah[ks], acc, 0, 0, 0);
                acc = __builtin_amdgcn_mfma_f32_16x16x32_bf16(whi[t][ks], Ah[ks], acc, 0, 0, 0);
            }
            const int c0 = col0 + 16 * t + lg * 4;
            f32x4 bv = {0.f, 0.f, 0.f, 0.f};
            if (bias) bv = *(const f32x4*)(bias + c0);
            bf16x4 h, l;
            #pragma unroll
            for (int r = 0; r < 4; r++) {
                float v = acc[r] + bv[r];
                if (relu_out) v = fmaxf(v, 0.f);
                h[r] = (bf16)v;
                l[r] = (bf16)(v - (float)h[r]);
            }
            size_t base = (size_t)(rt * 16 + l15) * 128 + c0;
            *(bf16x4*)(ohi + base) = h;
            if (olo) *(bf16x4*)(olo + base) = l;
        }
    }
}

// ---------------- MFMA GEMM, fp32 input (layer 1): split x in-register, hi-only out ----------------

__global__ __launch_bounds__(256) void gemm_mfma_x(
    const float* __restrict__ X, const float* __restrict__ W,
    bf16* __restrict__ ohi, int n_rows)
{
    const int lane = threadIdx.x & 63;
    const int wv   = threadIdx.x >> 6;
    const int col0 = wv * 32;
    const int l15  = lane & 15;
    const int lg   = lane >> 4;

    bf16x8 whi[2][4], wlo[2][4];
    #pragma unroll
    for (int t = 0; t < 2; t++) {
        int c = col0 + 16 * t + l15;
        #pragma unroll
        for (int ks = 0; ks < 4; ks++) {
            #pragma unroll
            for (int j = 0; j < 8; j++) {
                float wvv = W[(ks * 32 + lg * 8 + j) * 128 + c];
                bf16 h = (bf16)wvv;
                whi[t][ks][j] = h;
                wlo[t][ks][j] = (bf16)(wvv - (float)h);
            }
        }
    }

    const int nrt = n_rows >> 4;
    for (int rt = blockIdx.x; rt < nrt; rt += gridDim.x) {
        const int row = rt * 16 + l15;
        const float* px = X + (size_t)row * 128 + lg * 8;
        bf16x8 Ah[4], Al[4];
        #pragma unroll
        for (int ks = 0; ks < 4; ks++) {
            float4 v0 = *(const float4*)(px + ks * 32);
            float4 v1 = *(const float4*)(px + ks * 32 + 4);
            float vv[8] = {v0.x, v0.y, v0.z, v0.w, v1.x, v1.y, v1.z, v1.w};
            #pragma unroll
            for (int j = 0; j < 8; j++) {
                bf16 h = (bf16)vv[j];
                Ah[ks][j] = h;
                Al[ks][j] = (bf16)(vv[j] - (float)h);
            }
        }
        #pragma unroll
        for (int t = 0; t < 2; t++) {
            f32x4 acc = {0.f, 0.f, 0.f, 0.f};
            #pragma unroll
            for (int ks = 0; ks < 4; ks++) {
                acc = __builtin_amdgcn_mfma_f32_16x16x32_bf16(whi[t][ks], Al[ks], acc, 0, 0, 0);
                acc = __builtin_amdgcn_mfma_f32_16x16x32_bf16(wlo[t][ks], Ah[ks], acc, 0, 0, 0);
                acc = __builtin_amdgcn_mfma_f32_16x16x32_bf16(whi[t][ks], Ah[ks], acc, 0, 0, 0);
            }
            const int c0 = col0 + 16 * t + lg * 4;
            bf16x4 h;
            #pragma unroll
            for (int r = 0; r < 4; r++) h[r] = (bf16)acc[r];
            size_t base = (size_t)(rt * 16 + l15) * 128 + c0;
            *(bf16x4*)(ohi + base) = h;
        }
    }
}

// ---------------- CSR gather aggregation (hi-only in AND out) ----------------

__global__ __launch_bounds__(256) void gather_agg_split(
    const bf16* __restrict__ hhi,
    const uint2* __restrict__ erec, const int* __restrict__ off,
    const float* __restrict__ dinv, const float* __restrict__ bias,
    bf16* __restrict__ ohi, int n)
{
    int lane = threadIdx.x & 63;
    int wid  = (blockIdx.x * 256 + threadIdx.x) >> 6;
    int nw   = (gridDim.x * 256) >> 6;

    const int f = 2 * lane;
    float bb0 = bias[f], bb1 = bias[f + 1];

    for (int node = wid; node < n; node += nw) {
        float sn = dinv[node]; sn *= sn;
        size_t nb = (size_t)node * 128 + f;
        bf16x2 sh = *(const bf16x2*)(hhi + nb);
        float a0 = fmaf((float)sh[0], sn, bb0);
        float a1 = fmaf((float)sh[1], sn, bb1);

        int e0 = off[node], e1 = off[node + 1];
        int e = e0;
        for (; e + 8 <= e1; e += 8) {
            uint2 q[8];
            #pragma unroll
            for (int j = 0; j < 8; j++) q[j] = erec[e + j];
            bf16x2 r[8];
            #pragma unroll
            for (int j = 0; j < 8; j++)
                r[j] = *(const bf16x2*)(hhi + (size_t)q[j].x * 128 + f);
            #pragma unroll
            for (int j = 0; j < 8; j++) {
                float w = __uint_as_float(q[j].y);
                a0 = fmaf((float)r[j][0], w, a0);
                a1 = fmaf((float)r[j][1], w, a1);
            }
        }
        for (; e + 4 <= e1; e += 4) {
            uint2 q[4];
            #pragma unroll
            for (int j = 0; j < 4; j++) q[j] = erec[e + j];
            bf16x2 r[4];
            #pragma unroll
            for (int j = 0; j < 4; j++)
                r[j] = *(const bf16x2*)(hhi + (size_t)q[j].x * 128 + f);
            #pragma unroll
            for (int j = 0; j < 4; j++) {
                float w = __uint_as_float(q[j].y);
                a0 = fmaf((float)r[j][0], w, a0);
                a1 = fmaf((float)r[j][1], w, a1);
            }
        }
        for (; e < e1; e++) {
            uint2 q = erec[e];
            float w = __uint_as_float(q.y);
            bf16x2 r = *(const bf16x2*)(hhi + (size_t)q.x * 128 + f);
            a0 = fmaf((float)r[0], w, a0);
            a1 = fmaf((float)r[1], w, a1);
        }

        a0 = fmaxf(a0, 0.f);
        a1 = fmaxf(a1, 0.f);
        bf16x2 oh;
        oh[0] = (bf16)a0;
        oh[1] = (bf16)a1;
        *(bf16x2*)(ohi + nb) = oh;
    }
}

// ---------------- lin2 + log_softmax via MFMA (swapped operands) ----------------

__global__ __launch_bounds__(256) void lin2_mfma_lsm(
    const bf16* __restrict__ hhi, const bf16* __restrict__ hlo,
    const float* __restrict__ W, const float* __restrict__ bias,
    float* __restrict__ out, int n)
{
    const int lane = threadIdx.x & 63;
    const int l15  = lane & 15;
    const int lg   = lane >> 4;

    bf16x8 whi[3][4], wlo[3][4];
    #pragma unroll
    for (int t = 0; t < 3; t++) {
        int c = t * 16 + l15;
        bool valid = c < 40;
        #pragma unroll
        for (int ks = 0; ks < 4; ks++) {
            #pragma unroll
            for (int j = 0; j < 8; j++) {
                float wv = valid ? W[(ks * 32 + lg * 8 + j) * 40 + c] : 0.f;
                bf16 h = (bf16)wv;
                whi[t][ks][j] = h;
                wlo[t][ks][j] = (bf16)(wv - (float)h);
            }
        }
    }
    f32x4 bb[3];
    bool vstore[3];
    #pragma unroll
    for (int t = 0; t < 3; t++) {
        int c0 = t * 16 + lg * 4;
        vstore[t] = (c0 < 40);
        if (vstore[t]) bb[t] = *(const f32x4*)(bias + c0);
        else bb[t] = (f32x4){0.f, 0.f, 0.f, 0.f};
    }

    int wtile = (blockIdx.x * 256 + threadIdx.x) >> 6;
    int nwt   = (gridDim.x * 256) >> 6;
    int ntiles = (n + 15) >> 4;

    for (int rt = wtile; rt < ntiles; rt += nwt) {
        int arow = rt * 16 + l15;
        if (arow >= n) arow = n - 1;
        const bf16* pah = hhi + (size_t)arow * 128 + lg * 8;
        const bf16* pal = hlo + (size_t)arow * 128 + lg * 8;
        bf16x8 Ah[4], Al[4];
        #pragma unroll
        for (int ks = 0; ks < 4; ks++) {
            Ah[ks] = *(const bf16x8*)(pah + ks * 32);
            Al[ks] = *(const bf16x8*)(pal + ks * 32);
        }
        f32x4 acc[3];
        #pragma unroll
        for (int t = 0; t < 3; t++) {
            acc[t] = (f32x4){0.f, 0.f, 0.f, 0.f};
            #pragma unroll
            for (int ks = 0; ks < 4; ks++) {
                acc[t] = __builtin_amdgcn_mfma_f32_16x16x32_bf16(whi[t][ks], Al[ks], acc[t], 0, 0, 0);
                acc[t] = __builtin_amdgcn_mfma_f32_16x16x32_bf16(wlo[t][ks], Ah[ks], acc[t], 0, 0, 0);
                acc[t] = __builtin_amdgcn_mfma_f32_16x16x32_bf16(whi[t][ks], Ah[ks], acc[t], 0, 0, 0);
            }
        }
        float m = -INFINITY;
        #pragma unroll
        for (int t = 0; t < 3; t++) {
            if (vstore[t]) {
                #pragma unroll
                for (int r = 0; r < 4; r++) m = fmaxf(m, acc[t][r] + bb[t][r]);
            }
        }
        m = fmaxf(m, __shfl_xor(m, 16, 64));
        m = fmaxf(m, __shfl_xor(m, 32, 64));
        float s = 0.f;
        #pragma unroll
        for (int t = 0; t < 3; t++) {
            if (vstore[t]) {
                #pragma unroll
                for (int r = 0; r < 4; r++) s += __expf(acc[t][r] + bb[t][r] - m);
            }
        }
        s += __shfl_xor(s, 16, 64);
        s += __shfl_xor(s, 32, 64);
        float ls = __logf(s) + m;

        int node = rt * 16 + l15;
        if (node < n) {
            #pragma unroll
            for (int t = 0; t < 3; t++) {
                if (vstore[t]) {
                    f32x4 o;
                    #pragma unroll
                    for (int r = 0; r < 4; r++) o[r] = acc[t][r] + bb[t][r] - ls;
                    *(f32x4*)(out + (size_t)node * 40 + t * 16 + lg * 4) = o;
                }
            }
        }
    }
}

// ---------------- launch ----------------

static inline size_t align256(size_t x) { return (x + 255) & ~(size_t)255; }

extern "C" void kernel_launch(void* const* d_in, const int* in_sizes, int n_in,
                              void* d_out, int out_size, void* d_ws, size_t ws_size,
                              hipStream_t stream)
{
    const float* x   = (const float*)d_in[0];
    const int*   ei  = (const int*)d_in[1];
    const float* W1  = (const float*)d_in[2];  const float* b1  = (const float*)d_in[3];
    const float* W2  = (const float*)d_in[4];  const float* b2  = (const float*)d_in[5];
    const float* W3  = (const float*)d_in[6];  const float* b3  = (const float*)d_in[7];
    const float* l1w = (const float*)d_in[8];  const float* l1b = (const float*)d_in[9];
    const float* l2w = (const float*)d_in[10]; const float* l2b = (const float*)d_in[11];

    const int N = in_sizes[0] / 128;
    const int E = in_sizes[1] / 2;
    const int* src = ei;
    const int* dst = ei + E;

    char* wsb = (char*)d_ws;
    size_t o = 0;
    int*   gcur  = (int*)(wsb + o);   o = align256(o + (size_t)N * 4);        // fill_sort fallback cursors
    int*   off   = (int*)(wsb + o);   o = align256(o + (size_t)(N + 1) * 4);
    int*   bhist = (int*)(wsb + o);   o = align256(o + (size_t)512 * 4);
    int*   bcur  = (int*)(wsb + o);   o = align256(o + (size_t)512 * 4);
    int*   ebase = (int*)(wsb + o);   o = align256(o + (size_t)513 * 4);
    uint2* erec  = (uint2*)(wsb + o); o = align256(o + (size_t)E * 8);
    float* dinv  = (float*)(wsb + o); o = align256(o + (size_t)N * 4);
    bf16*  ahi   = (bf16*)(wsb + o);  o = align256(o + (size_t)N * 128 * 2);
    bf16*  hhi   = (bf16*)(wsb + o);  o = align256(o + (size_t)N * 128 * 2);
    bf16*  hlo   = (bf16*)(wsb + o);  o = align256(o + (size_t)N * 128 * 2);

    uint2* ebuf = (uint2*)hhi;   // dead until gemm1; 12.8MB < 25.6MB region

    float* outp = (float*)d_out;
    const int nbk  = (N + 255) >> BSH2;                 // 391 buckets
    const int npart = (E + PCH - 1) / PCH;              // 391 chunks

    // ---- CSR build: bucket hist, scan, partition, per-bucket off/dinv, counting sort ----
    zero_i32<<<(N + 255) / 256, 256, 0, stream>>>(gcur, N);
    zero_i32<<<4, 256, 0, stream>>>(bhist, 1024);       // bhist + bcur (contiguous)
    bhist_k<<<1024, 256, 0, stream>>>(dst, bhist, E);
    bscan512<<<1, 64, 0, stream>>>(bhist, ebase);
    partition_edges<<<npart, 256, 0, stream>>>(src, dst, ebase, bcur, ebuf, E, nbk);
    bucket_off_dinv<<<nbk, 256, 0, stream>>>(ebuf, ebase, off, dinv, N, nbk);
    fill_sort<<<nbk, 256, 0, stream>>>(ebuf, off, dinv, gcur, erec, N, nbk);

    // ---- layer 1: gemm directly from fp32 x (hi-only out) ----
    gemm_mfma_x<<<1024, 256, 0, stream>>>(x, W1, hhi, N);
    gather_agg_split<<<4096, 256, 0, stream>>>(hhi, erec, off, dinv, b1, ahi, N);

    // ---- layer 2 ----
    gemm_mfma<<<1024, 256, 0, stream>>>(ahi, W2, nullptr, hhi, nullptr, N, 0);
    gather_agg_split<<<4096, 256, 0, stream>>>(hhi, erec, off, dinv, b2, ahi, N);

    // ---- layer 3 ----
    gemm_mfma<<<1024, 256, 0, stream>>>(ahi, W3, nullptr, hhi, nullptr, N, 0);
    gather_agg_split<<<4096, 256, 0, stream>>>(hhi, erec, off, dinv, b3, ahi, N);

    // ---- lin1 (+bias+relu) -> full hi/lo split (lin2 precision) ----
    gemm_mfma<<<1024, 256, 0, stream>>>(ahi, l1w, l1b, hhi, hlo, N, 1);

    // ---- lin2 + log_softmax (MFMA, swapped) ----
    lin2_mfma_lsm<<<512, 256, 0, stream>>>(hhi, hlo, l2w, l2b, outp, N);
}

// Round 20
// 371.065 us; speedup vs baseline: 1.3611x; 1.0680x over previous
//
#include <hip/hip_runtime.h>
#include <math.h>

typedef __bf16 bf16;
typedef bf16  bf16x8 __attribute__((ext_vector_type(8)));
typedef bf16  bf16x4 __attribute__((ext_vector_type(4)));
typedef bf16  bf16x2 __attribute__((ext_vector_type(2)));
typedef float f32x4  __attribute__((ext_vector_type(4)));
typedef float f32x2  __attribute__((ext_vector_type(2)));

#define BSH2 8        // bucket = 256 nodes
#define PCH  4096     // edges per partition chunk (391 blocks)
#define CAP  4608     // LDS record capacity per bucket (mean 4096, 8 sigma margin)

// ---------------- helpers ----------------

__global__ void zero_i32(int* __restrict__ p, int n) {
    int i = blockIdx.x * blockDim.x + threadIdx.x;
    if (i < n) p[i] = 0;
}

// ---------------- bucket histogram of dst>>8 (sequential read, LDS hist) ----------------

__global__ __launch_bounds__(256) void bhist_k(const int* __restrict__ dst,
                                               int* __restrict__ bhist, int E) {
    __shared__ int lh[512];
    for (int b = threadIdx.x; b < 512; b += 256) lh[b] = 0;
    __syncthreads();
    int i = blockIdx.x * 256 + threadIdx.x;
    int stride = gridDim.x * 256;
    for (; i < E; i += stride) atomicAdd(&lh[dst[i] >> BSH2], 1);
    __syncthreads();
    for (int b = threadIdx.x; b < 512; b += 256)
        if (lh[b]) atomicAdd(&bhist[b], lh[b]);
}

// single wave: exclusive scan bhist[512] -> ebase[513]
__global__ __launch_bounds__(64) void bscan512(const int* __restrict__ bhist,
                                               int* __restrict__ ebase) {
    int lane = threadIdx.x;
    __shared__ int carry_s;
    if (lane == 0) carry_s = 0;
    __syncthreads();
    for (int base = 0; base < 512; base += 64) {
        int v = bhist[base + lane];
        int x = v;
        #pragma unroll
        for (int o = 1; o < 64; o <<= 1) {
            int t = __shfl_up(x, o, 64);
            if (lane >= o) x += t;
        }
        int carry = carry_s;
        ebase[base + lane] = carry + x - v;
        int total = __shfl(x, 63, 64);
        __syncthreads();
        if (lane == 0) carry_s = carry + total;
        __syncthreads();
    }
    if (lane == 0) ebase[512] = carry_s;
}

// ---------------- pass 1: partition edges by dst bucket, coalesced runs ----------------

__global__ __launch_bounds__(256) void partition_edges(
    const int* __restrict__ src, const int* __restrict__ dst,
    const int* __restrict__ ebase, int* __restrict__ bcur,
    uint2* __restrict__ ebuf, int E, int nbk)
{
    __shared__ int lhist[512];
    __shared__ int lbase[512];
    __shared__ int lcur[512];
    __shared__ int gbase[512];
    __shared__ int csum[8];
    __shared__ unsigned short stage[PCH];

    const int tid = threadIdx.x, lane = tid & 63, wv = tid >> 6;

    for (int base = blockIdx.x * PCH; base < E; base += gridDim.x * PCH) {
        const int cnt = min(PCH, E - base);

        for (int b = tid; b < 512; b += 256) lhist[b] = 0;
        __syncthreads();
        for (int i = tid; i < cnt; i += 256)
            atomicAdd(&lhist[dst[base + i] >> BSH2], 1);
        __syncthreads();
        for (int c = wv; c < 8; c += 4) {
            int idx = c * 64 + lane;
            int v = lhist[idx], x = v;
            #pragma unroll
            for (int o = 1; o < 64; o <<= 1) {
                int t = __shfl_up(x, o, 64);
                if (lane >= o) x += t;
            }
            lbase[idx] = x - v;
            if (lane == 63) csum[c] = x;
        }
        __syncthreads();
        if (tid == 0) {
            int acc = 0;
            #pragma unroll
            for (int c = 0; c < 8; c++) { int t = csum[c]; csum[c] = acc; acc += t; }
        }
        __syncthreads();
        for (int c = wv; c < 8; c += 4) {
            int idx = c * 64 + lane;
            lbase[idx] += csum[c];
            lcur[idx] = lbase[idx];
        }
        __syncthreads();
        for (int i = tid; i < cnt; i += 256) {
            int b = dst[base + i] >> BSH2;
            int p = atomicAdd(&lcur[b], 1);
            stage[p] = (unsigned short)i;
        }
        __syncthreads();
        for (int b = tid; b < nbk; b += 256) {
            int cb = lcur[b] - lbase[b];
            if (cb > 0) gbase[b] = ebase[b] + atomicAdd(&bcur[b], cb);
        }
        __syncthreads();
        for (int k = tid; k < cnt; k += 256) {
            int i = base + (int)stage[k];
            int s = src[i], d = dst[i];
            int b = d >> BSH2;
            ebuf[gbase[b] + (k - lbase[b])] = make_uint2((unsigned)s, (unsigned)d);
        }
        __syncthreads();
    }
}

// ---------------- pass 1.5: per-bucket deg count -> off[] and dinv[] ----------------

__global__ __launch_bounds__(256) void bucket_off_dinv(
    const uint2* __restrict__ ebuf, const int* __restrict__ ebase,
    int* __restrict__ off, float* __restrict__ dinv, int n, int nbk)
{
    __shared__ int ldeg[256];
    __shared__ int wsum[4];
    const int tid = threadIdx.x, lane = tid & 63, wv = tid >> 6;

    for (int b = blockIdx.x; b < nbk; b += gridDim.x) {
        const int n0 = b << BSH2;
        const int n1 = min(n0 + 256, n);
        const int e0 = ebase[b], e1 = ebase[b + 1];

        ldeg[tid] = 0;
        __syncthreads();
        for (int i = e0 + tid; i < e1; i += 256)
            atomicAdd(&ldeg[(int)ebuf[i].y - n0], 1);
        __syncthreads();

        int v = ldeg[tid];
        int x = v;
        #pragma unroll
        for (int o = 1; o < 64; o <<= 1) {
            int t = __shfl_up(x, o, 64);
            if (lane >= o) x += t;
        }
        if (lane == 63) wsum[wv] = x;
        __syncthreads();
        int wbase = 0;
        #pragma unroll
        for (int w = 0; w < 4; w++) if (w < wv) wbase += wsum[w];
        int pref = wbase + x - v;   // exclusive prefix

        if (n0 + tid < n1) {
            off[n0 + tid]  = e0 + pref;
            dinv[n0 + tid] = rsqrtf((float)v + 1.0f);
        }
        __syncthreads();
    }
    if (blockIdx.x == 0 && threadIdx.x == 0) off[n] = ebase[nbk];
}

// ---------------- pass 2: per-bucket LDS counting sort -> coalesced erec write ----------------

__global__ __launch_bounds__(256) void fill_sort(
    const uint2* __restrict__ ebuf, const int* __restrict__ off,
    const float* __restrict__ dinv, int* __restrict__ gcur,
    uint2* __restrict__ erec, int n, int nbk)
{
    __shared__ int  lcur[256];
    __shared__ uint2 lrec[CAP];   // 36 KB

    for (int b = blockIdx.x; b < nbk; b += gridDim.x) {
        const int n0 = b << BSH2;
        const int n1 = min(n0 + 256, n);
        const int e0 = off[n0], e1 = off[n1];
        const int cnt = e1 - e0;
        if (threadIdx.x < (unsigned)(n1 - n0))
            lcur[threadIdx.x] = off[n0 + threadIdx.x] - e0;
        __syncthreads();
        if (cnt <= CAP) {
            for (int i = threadIdx.x; i < cnt; i += 256) {
                uint2 q = ebuf[e0 + i];
                int s = (int)q.x, d = (int)q.y;
                int p = atomicAdd(&lcur[d - n0], 1);
                lrec[p] = make_uint2(q.x, (unsigned)__float_as_uint(dinv[s] * dinv[d]));
            }
            __syncthreads();
            for (int i = threadIdx.x; i < cnt; i += 256)
                erec[e0 + i] = lrec[i];
        } else {
            for (int i = threadIdx.x; i < cnt; i += 256) {
                uint2 q = ebuf[e0 + i];
                int s = (int)q.x, d = (int)q.y;
                int p = off[d] + atomicAdd(&gcur[d], 1);
                erec[p] = make_uint2(q.x, (unsigned)__float_as_uint(dinv[s] * dinv[d]));
            }
        }
        __syncthreads();
    }
}

// ---------------- MFMA GEMM (swapped operands), bf16-hi activation input ----------------
// 2-term: C^T = (Whi + Wlo)^T @ Ah^T. Writes bf16 hi; optional fp8 mirror hq
// (gather message source); optional lo (lin1 -> lin2 precision).

__global__ __launch_bounds__(256) void gemm_mfma(
    const bf16* __restrict__ ahi,
    const float* __restrict__ W, const float* __restrict__ bias,
    bf16* __restrict__ ohi, bf16* __restrict__ olo,
    unsigned char* __restrict__ oq, int n_rows, int relu_out)
{
    const int lane = threadIdx.x & 63;
    const int wv   = threadIdx.x >> 6;
    const int col0 = wv * 32;
    const int l15  = lane & 15;
    const int lg   = lane >> 4;

    bf16x8 whi[2][4], wlo[2][4];
    #pragma unroll
    for (int t = 0; t < 2; t++) {
        int c = col0 + 16 * t + l15;
        #pragma unroll
        for (int ks = 0; ks < 4; ks++) {
            #pragma unroll
            for (int j = 0; j < 8; j++) {
                float wvv = W[(ks * 32 + lg * 8 + j) * 128 + c];
                bf16 h = (bf16)wvv;
                whi[t][ks][j] = h;
                wlo[t][ks][j] = (bf16)(wvv - (float)h);
            }
        }
    }

    const int nrt = n_rows >> 4;
    for (int rt = blockIdx.x; rt < nrt; rt += gridDim.x) {
        const int row = rt * 16 + l15;
        const bf16* pah = ahi + (size_t)row * 128 + lg * 8;
        bf16x8 Ah[4];
        #pragma unroll
        for (int ks = 0; ks < 4; ks++)
            Ah[ks] = *(const bf16x8*)(pah + ks * 32);
        #pragma unroll
        for (int t = 0; t < 2; t++) {
            f32x4 acc = {0.f, 0.f, 0.f, 0.f};
            #pragma unroll
            for (int ks = 0; ks < 4; ks++) {
                acc = __builtin_amdgcn_mfma_f32_16x16x32_bf16(wlo[t][ks], Ah[ks], acc, 0, 0, 0);
                acc = __builtin_amdgcn_mfma_f32_16x16x32_bf16(whi[t][ks], Ah[ks], acc, 0, 0, 0);
            }
            const int c0 = col0 + 16 * t + lg * 4;
            f32x4 bv = {0.f, 0.f, 0.f, 0.f};
            if (bias) bv = *(const f32x4*)(bias + c0);
            float v0 = acc[0] + bv[0], v1 = acc[1] + bv[1];
            float v2 = acc[2] + bv[2], v3 = acc[3] + bv[3];
            if (relu_out) {
                v0 = fmaxf(v0, 0.f); v1 = fmaxf(v1, 0.f);
                v2 = fmaxf(v2, 0.f); v3 = fmaxf(v3, 0.f);
            }
            size_t base = (size_t)(rt * 16 + l15) * 128 + c0;
            bf16x4 h, l;
            h[0] = (bf16)v0; h[1] = (bf16)v1; h[2] = (bf16)v2; h[3] = (bf16)v3;
            *(bf16x4*)(ohi + base) = h;
            if (olo) {
                l[0] = (bf16)(v0 - (float)h[0]);
                l[1] = (bf16)(v1 - (float)h[1]);
                l[2] = (bf16)(v2 - (float)h[2]);
                l[3] = (bf16)(v3 - (float)h[3]);
                *(bf16x4*)(olo + base) = l;
            }
            if (oq) {
                int p = __builtin_amdgcn_cvt_pk_fp8_f32(v0, v1, 0, false);
                p = __builtin_amdgcn_cvt_pk_fp8_f32(v2, v3, p, true);
                *(unsigned int*)(oq + base) = (unsigned int)p;
            }
        }
    }
}

// ---------------- MFMA GEMM, fp32 input (layer 1): split x in-register ----------------
// Writes bf16 hi + fp8 mirror.

__global__ __launch_bounds__(256) void gemm_mfma_x(
    const float* __restrict__ X, const float* __restrict__ W,
    bf16* __restrict__ ohi, unsigned char* __restrict__ oq, int n_rows)
{
    const int lane = threadIdx.x & 63;
    const int wv   = threadIdx.x >> 6;
    const int col0 = wv * 32;
    const int l15  = lane & 15;
    const int lg   = lane >> 4;

    bf16x8 whi[2][4], wlo[2][4];
    #pragma unroll
    for (int t = 0; t < 2; t++) {
        int c = col0 + 16 * t + l15;
        #pragma unroll
        for (int ks = 0; ks < 4; ks++) {
            #pragma unroll
            for (int j = 0; j < 8; j++) {
                float wvv = W[(ks * 32 + lg * 8 + j) * 128 + c];
                bf16 h = (bf16)wvv;
                whi[t][ks][j] = h;
                wlo[t][ks][j] = (bf16)(wvv - (float)h);
            }
        }
    }

    const int nrt = n_rows >> 4;
    for (int rt = blockIdx.x; rt < nrt; rt += gridDim.x) {
        const int row = rt * 16 + l15;
        const float* px = X + (size_t)row * 128 + lg * 8;
        bf16x8 Ah[4], Al[4];
        #pragma unroll
        for (int ks = 0; ks < 4; ks++) {
            float4 v0 = *(const float4*)(px + ks * 32);
            float4 v1 = *(const float4*)(px + ks * 32 + 4);
            float vv[8] = {v0.x, v0.y, v0.z, v0.w, v1.x, v1.y, v1.z, v1.w};
            #pragma unroll
            for (int j = 0; j < 8; j++) {
                bf16 h = (bf16)vv[j];
                Ah[ks][j] = h;
                Al[ks][j] = (bf16)(vv[j] - (float)h);
            }
        }
        #pragma unroll
        for (int t = 0; t < 2; t++) {
            f32x4 acc = {0.f, 0.f, 0.f, 0.f};
            #pragma unroll
            for (int ks = 0; ks < 4; ks++) {
                acc = __builtin_amdgcn_mfma_f32_16x16x32_bf16(whi[t][ks], Al[ks], acc, 0, 0, 0);
                acc = __builtin_amdgcn_mfma_f32_16x16x32_bf16(wlo[t][ks], Ah[ks], acc, 0, 0, 0);
                acc = __builtin_amdgcn_mfma_f32_16x16x32_bf16(whi[t][ks], Ah[ks], acc, 0, 0, 0);
            }
            const int c0 = col0 + 16 * t + lg * 4;
            size_t base = (size_t)(rt * 16 + l15) * 128 + c0;
            bf16x4 h;
            #pragma unroll
            for (int r = 0; r < 4; r++) h[r] = (bf16)acc[r];
            *(bf16x4*)(ohi + base) = h;
            int p = __builtin_amdgcn_cvt_pk_fp8_f32(acc[0], acc[1], 0, false);
            p = __builtin_amdgcn_cvt_pk_fp8_f32(acc[2], acc[3], p, true);
            *(unsigned int*)(oq + base) = (unsigned int)p;
        }
    }
}

// ---------------- CSR gather aggregation: fp8 messages, bf16 self, bf16-hi out ----------------

__global__ __launch_bounds__(256) void gather_agg_split(
    const bf16* __restrict__ hhi, const unsigned char* __restrict__ hq,
    const uint2* __restrict__ erec, const int* __restrict__ off,
    const float* __restrict__ dinv, const float* __restrict__ bias,
    bf16* __restrict__ ohi, int n)
{
    int lane = threadIdx.x & 63;
    int wid  = (blockIdx.x * 256 + threadIdx.x) >> 6;
    int nw   = (gridDim.x * 256) >> 6;

    const int f = 2 * lane;
    float bb0 = bias[f], bb1 = bias[f + 1];

    for (int node = wid; node < n; node += nw) {
        float sn = dinv[node]; sn *= sn;
        size_t nb = (size_t)node * 128 + f;
        bf16x2 sh = *(const bf16x2*)(hhi + nb);
        float a0 = fmaf((float)sh[0], sn, bb0);
        float a1 = fmaf((float)sh[1], sn, bb1);

        int e0 = off[node], e1 = off[node + 1];
        int e = e0;
        for (; e + 8 <= e1; e += 8) {
            uint2 q[8];
            #pragma unroll
            for (int j = 0; j < 8; j++) q[j] = erec[e + j];
            unsigned short rw[8];
            #pragma unroll
            for (int j = 0; j < 8; j++)
                rw[j] = *(const unsigned short*)(hq + (size_t)q[j].x * 128 + f);
            #pragma unroll
            for (int j = 0; j < 8; j++) {
                float w = __uint_as_float(q[j].y);
                f32x2 mv = __builtin_amdgcn_cvt_pk_f32_fp8((int)(unsigned)rw[j], false);
                a0 = fmaf(mv[0], w, a0);
                a1 = fmaf(mv[1], w, a1);
            }
        }
        for (; e + 4 <= e1; e += 4) {
            uint2 q[4];
            #pragma unroll
            for (int j = 0; j < 4; j++) q[j] = erec[e + j];
            unsigned short rw[4];
            #pragma unroll
            for (int j = 0; j < 4; j++)
                rw[j] = *(const unsigned short*)(hq + (size_t)q[j].x * 128 + f);
            #pragma unroll
            for (int j = 0; j < 4; j++) {
                float w = __uint_as_float(q[j].y);
                f32x2 mv = __builtin_amdgcn_cvt_pk_f32_fp8((int)(unsigned)rw[j], false);
                a0 = fmaf(mv[0], w, a0);
                a1 = fmaf(mv[1], w, a1);
            }
        }
        for (; e < e1; e++) {
            uint2 q = erec[e];
            float w = __uint_as_float(q.y);
            unsigned short rwv = *(const unsigned short*)(hq + (size_t)q.x * 128 + f);
            f32x2 mv = __builtin_amdgcn_cvt_pk_f32_fp8((int)(unsigned)rwv, false);
            a0 = fmaf(mv[0], w, a0);
            a1 = fmaf(mv[1], w, a1);
        }

        a0 = fmaxf(a0, 0.f);
        a1 = fmaxf(a1, 0.f);
        bf16x2 oh;
        oh[0] = (bf16)a0;
        oh[1] = (bf16)a1;
        *(bf16x2*)(ohi + nb) = oh;
    }
}

// ---------------- lin2 + log_softmax via MFMA (swapped operands) ----------------

__global__ __launch_bounds__(256) void lin2_mfma_lsm(
    const bf16* __restrict__ hhi, const bf16* __restrict__ hlo,
    const float* __restrict__ W, const float* __restrict__ bias,
    float* __restrict__ out, int n)
{
    const int lane = threadIdx.x & 63;
    const int l15  = lane & 15;
    const int lg   = lane >> 4;

    bf16x8 whi[3][4], wlo[3][4];
    #pragma unroll
    for (int t = 0; t < 3; t++) {
        int c = t * 16 + l15;
        bool valid = c < 40;
        #pragma unroll
        for (int ks = 0; ks < 4; ks++) {
            #pragma unroll
            for (int j = 0; j < 8; j++) {
                float wv = valid ? W[(ks * 32 + lg * 8 + j) * 40 + c] : 0.f;
                bf16 h = (bf16)wv;
                whi[t][ks][j] = h;
                wlo[t][ks][j] = (bf16)(wv - (float)h);
            }
        }
    }
    f32x4 bb[3];
    bool vstore[3];
    #pragma unroll
    for (int t = 0; t < 3; t++) {
        int c0 = t * 16 + lg * 4;
        vstore[t] = (c0 < 40);
        if (vstore[t]) bb[t] = *(const f32x4*)(bias + c0);
        else bb[t] = (f32x4){0.f, 0.f, 0.f, 0.f};
    }

    int wtile = (blockIdx.x * 256 + threadIdx.x) >> 6;
    int nwt   = (gridDim.x * 256) >> 6;
    int ntiles = (n + 15) >> 4;

    for (int rt = wtile; rt < ntiles; rt += nwt) {
        int arow = rt * 16 + l15;
        if (arow >= n) arow = n - 1;
        const bf16* pah = hhi + (size_t)arow * 128 + lg * 8;
        const bf16* pal = hlo + (size_t)arow * 128 + lg * 8;
        bf16x8 Ah[4], Al[4];
        #pragma unroll
        for (int ks = 0; ks < 4; ks++) {
            Ah[ks] = *(const bf16x8*)(pah + ks * 32);
            Al[ks] = *(const bf16x8*)(pal + ks * 32);
        }
        f32x4 acc[3];
        #pragma unroll
        for (int t = 0; t < 3; t++) {
            acc[t] = (f32x4){0.f, 0.f, 0.f, 0.f};
            #pragma unroll
            for (int ks = 0; ks < 4; ks++) {
                acc[t] = __builtin_amdgcn_mfma_f32_16x16x32_bf16(whi[t][ks], Al[ks], acc[t], 0, 0, 0);
                acc[t] = __builtin_amdgcn_mfma_f32_16x16x32_bf16(wlo[t][ks], Ah[ks], acc[t], 0, 0, 0);
                acc[t] = __builtin_amdgcn_mfma_f32_16x16x32_bf16(whi[t][ks], Ah[ks], acc[t], 0, 0, 0);
            }
        }
        float m = -INFINITY;
        #pragma unroll
        for (int t = 0; t < 3; t++) {
            if (vstore[t]) {
                #pragma unroll
                for (int r = 0; r < 4; r++) m = fmaxf(m, acc[t][r] + bb[t][r]);
            }
        }
        m = fmaxf(m, __shfl_xor(m, 16, 64));
        m = fmaxf(m, __shfl_xor(m, 32, 64));
        float s = 0.f;
        #pragma unroll
        for (int t = 0; t < 3; t++) {
            if (vstore[t]) {
                #pragma unroll
                for (int r = 0; r < 4; r++) s += __expf(acc[t][r] + bb[t][r] - m);
            }
        }
        s += __shfl_xor(s, 16, 64);
        s += __shfl_xor(s, 32, 64);
        float ls = __logf(s) + m;

        int node = rt * 16 + l15;
        if (node < n) {
            #pragma unroll
            for (int t = 0; t < 3; t++) {
                if (vstore[t]) {
                    f32x4 o;
                    #pragma unroll
                    for (int r = 0; r < 4; r++) o[r] = acc[t][r] + bb[t][r] - ls;
                    *(f32x4*)(out + (size_t)node * 40 + t * 16 + lg * 4) = o;
                }
            }
        }
    }
}

// ---------------- launch ----------------

static inline size_t align256(size_t x) { return (x + 255) & ~(size_t)255; }

extern "C" void kernel_launch(void* const* d_in, const int* in_sizes, int n_in,
                              void* d_out, int out_size, void* d_ws, size_t ws_size,
                              hipStream_t stream)
{
    const float* x   = (const float*)d_in[0];
    const int*   ei  = (const int*)d_in[1];
    const float* W1  = (const float*)d_in[2];  const float* b1  = (const float*)d_in[3];
    const float* W2  = (const float*)d_in[4];  const float* b2  = (const float*)d_in[5];
    const float* W3  = (const float*)d_in[6];  const float* b3  = (const float*)d_in[7];
    const float* l1w = (const float*)d_in[8];  const float* l1b = (const float*)d_in[9];
    const float* l2w = (const float*)d_in[10]; const float* l2b = (const float*)d_in[11];

    const int N = in_sizes[0] / 128;
    const int E = in_sizes[1] / 2;
    const int* src = ei;
    const int* dst = ei + E;

    char* wsb = (char*)d_ws;
    size_t o = 0;
    int*   gcur  = (int*)(wsb + o);   o = align256(o + (size_t)N * 4);        // fill_sort fallback cursors
    int*   off   = (int*)(wsb + o);   o = align256(o + (size_t)(N + 1) * 4);
    int*   bhist = (int*)(wsb + o);   o = align256(o + (size_t)512 * 4);
    int*   bcur  = (int*)(wsb + o);   o = align256(o + (size_t)512 * 4);
    int*   ebase = (int*)(wsb + o);   o = align256(o + (size_t)513 * 4);
    uint2* erec  = (uint2*)(wsb + o); o = align256(o + (size_t)E * 8);
    float* dinv  = (float*)(wsb + o); o = align256(o + (size_t)N * 4);
    bf16*  ahi   = (bf16*)(wsb + o);  o = align256(o + (size_t)N * 128 * 2);
    bf16*  hhi   = (bf16*)(wsb + o);  o = align256(o + (size_t)N * 128 * 2);
    bf16*  hlo   = (bf16*)(wsb + o);  o = align256(o + (size_t)N * 128 * 2);
    unsigned char* hq = (unsigned char*)(wsb + o); o = align256(o + (size_t)N * 128);

    uint2* ebuf = (uint2*)hhi;   // dead until gemm1; 12.8MB < 25.6MB region

    float* outp = (float*)d_out;
    const int nbk  = (N + 255) >> BSH2;                 // 391 buckets
    const int npart = (E + PCH - 1) / PCH;              // 391 chunks

    // ---- CSR build: bucket hist, scan, partition, per-bucket off/dinv, counting sort ----
    zero_i32<<<(N + 255) / 256, 256, 0, stream>>>(gcur, N);
    zero_i32<<<4, 256, 0, stream>>>(bhist, 1024);       // bhist + bcur (contiguous)
    bhist_k<<<1024, 256, 0, stream>>>(dst, bhist, E);
    bscan512<<<1, 64, 0, stream>>>(bhist, ebase);
    partition_edges<<<npart, 256, 0, stream>>>(src, dst, ebase, bcur, ebuf, E, nbk);
    bucket_off_dinv<<<nbk, 256, 0, stream>>>(ebuf, ebase, off, dinv, N, nbk);
    fill_sort<<<nbk, 256, 0, stream>>>(ebuf, off, dinv, gcur, erec, N, nbk);

    // ---- layer 1: gemm from fp32 x -> bf16 hi + fp8 mirror ----
    gemm_mfma_x<<<1024, 256, 0, stream>>>(x, W1, hhi, hq, N);
    gather_agg_split<<<4096, 256, 0, stream>>>(hhi, hq, erec, off, dinv, b1, ahi, N);

    // ---- layer 2 ----
    gemm_mfma<<<1024, 256, 0, stream>>>(ahi, W2, nullptr, hhi, nullptr, hq, N, 0);
    gather_agg_split<<<4096, 256, 0, stream>>>(hhi, hq, erec, off, dinv, b2, ahi, N);

    // ---- layer 3 ----
    gemm_mfma<<<1024, 256, 0, stream>>>(ahi, W3, nullptr, hhi, nullptr, hq, N, 0);
    gather_agg_split<<<4096, 256, 0, stream>>>(hhi, hq, erec, off, dinv, b3, ahi, N);

    // ---- lin1 (+bias+relu) -> full hi/lo split (lin2 precision) ----
    gemm_mfma<<<1024, 256, 0, stream>>>(ahi, l1w, l1b, hhi, hlo, nullptr, N, 1);

    // ---- lin2 + log_softmax (MFMA, swapped) ----
    lin2_mfma_lsm<<<512, 256, 0, stream>>>(hhi, hlo, l2w, l2b, outp, N);
}

// Round 21
// 344.962 us; speedup vs baseline: 1.4641x; 1.0757x over previous
//
#include <hip/hip_runtime.h>
#include <math.h>

typedef __bf16 bf16;
typedef bf16  bf16x8 __attribute__((ext_vector_type(8)));
typedef bf16  bf16x4 __attribute__((ext_vector_type(4)));
typedef bf16  bf16x2 __attribute__((ext_vector_type(2)));
typedef float f32x4  __attribute__((ext_vector_type(4)));
typedef float f32x2  __attribute__((ext_vector_type(2)));

#define BSH2 8        // bucket = 256 nodes
#define PCH  4096     // edges per partition chunk (391 blocks)
#define CAP  4608     // LDS record capacity per bucket (mean 4096, 8 sigma margin)

// ---------------- helpers ----------------

__global__ void zero_i32(int* __restrict__ p, int n) {
    int i = blockIdx.x * blockDim.x + threadIdx.x;
    if (i < n) p[i] = 0;
}

// ---------------- bucket histogram of dst>>8 (sequential read, LDS hist) ----------------

__global__ __launch_bounds__(256) void bhist_k(const int* __restrict__ dst,
                                               int* __restrict__ bhist, int E) {
    __shared__ int lh[512];
    for (int b = threadIdx.x; b < 512; b += 256) lh[b] = 0;
    __syncthreads();
    int i = blockIdx.x * 256 + threadIdx.x;
    int stride = gridDim.x * 256;
    for (; i < E; i += stride) atomicAdd(&lh[dst[i] >> BSH2], 1);
    __syncthreads();
    for (int b = threadIdx.x; b < 512; b += 256)
        if (lh[b]) atomicAdd(&bhist[b], lh[b]);
}

// single wave: exclusive scan bhist[512] -> ebase[513]
__global__ __launch_bounds__(64) void bscan512(const int* __restrict__ bhist,
                                               int* __restrict__ ebase) {
    int lane = threadIdx.x;
    __shared__ int carry_s;
    if (lane == 0) carry_s = 0;
    __syncthreads();
    for (int base = 0; base < 512; base += 64) {
        int v = bhist[base + lane];
        int x = v;
        #pragma unroll
        for (int o = 1; o < 64; o <<= 1) {
            int t = __shfl_up(x, o, 64);
            if (lane >= o) x += t;
        }
        int carry = carry_s;
        ebase[base + lane] = carry + x - v;
        int total = __shfl(x, 63, 64);
        __syncthreads();
        if (lane == 0) carry_s = carry + total;
        __syncthreads();
    }
    if (lane == 0) ebase[512] = carry_s;
}

// ---------------- pass 1: partition edges by dst bucket, coalesced runs ----------------

__global__ __launch_bounds__(256) void partition_edges(
    const int* __restrict__ src, const int* __restrict__ dst,
    const int* __restrict__ ebase, int* __restrict__ bcur,
    uint2* __restrict__ ebuf, int E, int nbk)
{
    __shared__ int lhist[512];
    __shared__ int lbase[512];
    __shared__ int lcur[512];
    __shared__ int gbase[512];
    __shared__ int csum[8];
    __shared__ unsigned short stage[PCH];

    const int tid = threadIdx.x, lane = tid & 63, wv = tid >> 6;

    for (int base = blockIdx.x * PCH; base < E; base += gridDim.x * PCH) {
        const int cnt = min(PCH, E - base);

        for (int b = tid; b < 512; b += 256) lhist[b] = 0;
        __syncthreads();
        for (int i = tid; i < cnt; i += 256)
            atomicAdd(&lhist[dst[base + i] >> BSH2], 1);
        __syncthreads();
        for (int c = wv; c < 8; c += 4) {
            int idx = c * 64 + lane;
            int v = lhist[idx], x = v;
            #pragma unroll
            for (int o = 1; o < 64; o <<= 1) {
                int t = __shfl_up(x, o, 64);
                if (lane >= o) x += t;
            }
            lbase[idx] = x - v;
            if (lane == 63) csum[c] = x;
        }
        __syncthreads();
        if (tid == 0) {
            int acc = 0;
            #pragma unroll
            for (int c = 0; c < 8; c++) { int t = csum[c]; csum[c] = acc; acc += t; }
        }
        __syncthreads();
        for (int c = wv; c < 8; c += 4) {
            int idx = c * 64 + lane;
            lbase[idx] += csum[c];
            lcur[idx] = lbase[idx];
        }
        __syncthreads();
        for (int i = tid; i < cnt; i += 256) {
            int b = dst[base + i] >> BSH2;
            int p = atomicAdd(&lcur[b], 1);
            stage[p] = (unsigned short)i;
        }
        __syncthreads();
        for (int b = tid; b < nbk; b += 256) {
            int cb = lcur[b] - lbase[b];
            if (cb > 0) gbase[b] = ebase[b] + atomicAdd(&bcur[b], cb);
        }
        __syncthreads();
        for (int k = tid; k < cnt; k += 256) {
            int i = base + (int)stage[k];
            int s = src[i], d = dst[i];
            int b = d >> BSH2;
            ebuf[gbase[b] + (k - lbase[b])] = make_uint2((unsigned)s, (unsigned)d);
        }
        __syncthreads();
    }
}

// ---------------- pass 1.5: per-bucket deg count -> off[] and dinv[]; zeroes gcur ----------------

__global__ __launch_bounds__(256) void bucket_off_dinv(
    const uint2* __restrict__ ebuf, const int* __restrict__ ebase,
    int* __restrict__ off, float* __restrict__ dinv, int* __restrict__ gcur,
    int n, int nbk)
{
    __shared__ int ldeg[256];
    __shared__ int wsum[4];
    const int tid = threadIdx.x, lane = tid & 63, wv = tid >> 6;

    for (int b = blockIdx.x; b < nbk; b += gridDim.x) {
        const int n0 = b << BSH2;
        const int n1 = min(n0 + 256, n);
        const int e0 = ebase[b], e1 = ebase[b + 1];

        ldeg[tid] = 0;
        __syncthreads();
        for (int i = e0 + tid; i < e1; i += 256)
            atomicAdd(&ldeg[(int)ebuf[i].y - n0], 1);
        __syncthreads();

        int v = ldeg[tid];
        int x = v;
        #pragma unroll
        for (int o = 1; o < 64; o <<= 1) {
            int t = __shfl_up(x, o, 64);
            if (lane >= o) x += t;
        }
        if (lane == 63) wsum[wv] = x;
        __syncthreads();
        int wbase = 0;
        #pragma unroll
        for (int w = 0; w < 4; w++) if (w < wv) wbase += wsum[w];
        int pref = wbase + x - v;   // exclusive prefix

        if (n0 + tid < n1) {
            off[n0 + tid]  = e0 + pref;
            dinv[n0 + tid] = rsqrtf((float)v + 1.0f);
            gcur[n0 + tid] = 0;
        }
        __syncthreads();
    }
    if (blockIdx.x == 0 && threadIdx.x == 0) off[n] = ebase[nbk];
}

// ---------------- pass 2: per-bucket LDS counting sort -> coalesced erec write ----------------

__global__ __launch_bounds__(256) void fill_sort(
    const uint2* __restrict__ ebuf, const int* __restrict__ off,
    const float* __restrict__ dinv, int* __restrict__ gcur,
    uint2* __restrict__ erec, int n, int nbk)
{
    __shared__ int  lcur[256];
    __shared__ uint2 lrec[CAP];   // 36 KB

    for (int b = blockIdx.x; b < nbk; b += gridDim.x) {
        const int n0 = b << BSH2;
        const int n1 = min(n0 + 256, n);
        const int e0 = off[n0], e1 = off[n1];
        const int cnt = e1 - e0;
        if (threadIdx.x < (unsigned)(n1 - n0))
            lcur[threadIdx.x] = off[n0 + threadIdx.x] - e0;
        __syncthreads();
        if (cnt <= CAP) {
            for (int i = threadIdx.x; i < cnt; i += 256) {
                uint2 q = ebuf[e0 + i];
                int s = (int)q.x, d = (int)q.y;
                int p = atomicAdd(&lcur[d - n0], 1);
                lrec[p] = make_uint2(q.x, (unsigned)__float_as_uint(dinv[s] * dinv[d]));
            }
            __syncthreads();
            for (int i = threadIdx.x; i < cnt; i += 256)
                erec[e0 + i] = lrec[i];
        } else {
            for (int i = threadIdx.x; i < cnt; i += 256) {
                uint2 q = ebuf[e0 + i];
                int s = (int)q.x, d = (int)q.y;
                int p = off[d] + atomicAdd(&gcur[d], 1);
                erec[p] = make_uint2(q.x, (unsigned)__float_as_uint(dinv[s] * dinv[d]));
            }
        }
        __syncthreads();
    }
}

// ---------------- MFMA GEMM (swapped operands), bf16 activation input ----------------
// 2-term: C^T = (Whi + Wlo)^T @ Ah^T. Output targets all optional:
// ohi (bf16, lin1->lin2), oq (fp8 mirror, conv hidden state).

__global__ __launch_bounds__(256) void gemm_mfma(
    const bf16* __restrict__ ahi,
    const float* __restrict__ W, const float* __restrict__ bias,
    bf16* __restrict__ ohi, unsigned char* __restrict__ oq,
    int n_rows, int relu_out)
{
    const int lane = threadIdx.x & 63;
    const int wv   = threadIdx.x >> 6;
    const int col0 = wv * 32;
    const int l15  = lane & 15;
    const int lg   = lane >> 4;

    bf16x8 whi[2][4], wlo[2][4];
    #pragma unroll
    for (int t = 0; t < 2; t++) {
        int c = col0 + 16 * t + l15;
        #pragma unroll
        for (int ks = 0; ks < 4; ks++) {
            #pragma unroll
            for (int j = 0; j < 8; j++) {
                float wvv = W[(ks * 32 + lg * 8 + j) * 128 + c];
                bf16 h = (bf16)wvv;
                whi[t][ks][j] = h;
                wlo[t][ks][j] = (bf16)(wvv - (float)h);
            }
        }
    }

    const int nrt = n_rows >> 4;
    for (int rt = blockIdx.x; rt < nrt; rt += gridDim.x) {
        const int row = rt * 16 + l15;
        const bf16* pah = ahi + (size_t)row * 128 + lg * 8;
        bf16x8 Ah[4];
        #pragma unroll
        for (int ks = 0; ks < 4; ks++)
            Ah[ks] = *(const bf16x8*)(pah + ks * 32);
        #pragma unroll
        for (int t = 0; t < 2; t++) {
            f32x4 acc = {0.f, 0.f, 0.f, 0.f};
            #pragma unroll
            for (int ks = 0; ks < 4; ks++) {
                acc = __builtin_amdgcn_mfma_f32_16x16x32_bf16(wlo[t][ks], Ah[ks], acc, 0, 0, 0);
                acc = __builtin_amdgcn_mfma_f32_16x16x32_bf16(whi[t][ks], Ah[ks], acc, 0, 0, 0);
            }
            const int c0 = col0 + 16 * t + lg * 4;
            f32x4 bv = {0.f, 0.f, 0.f, 0.f};
            if (bias) bv = *(const f32x4*)(bias + c0);
            float v0 = acc[0] + bv[0], v1 = acc[1] + bv[1];
            float v2 = acc[2] + bv[2], v3 = acc[3] + bv[3];
            if (relu_out) {
                v0 = fmaxf(v0, 0.f); v1 = fmaxf(v1, 0.f);
                v2 = fmaxf(v2, 0.f); v3 = fmaxf(v3, 0.f);
            }
            size_t base = (size_t)(rt * 16 + l15) * 128 + c0;
            if (ohi) {
                bf16x4 h;
                h[0] = (bf16)v0; h[1] = (bf16)v1; h[2] = (bf16)v2; h[3] = (bf16)v3;
                *(bf16x4*)(ohi + base) = h;
            }
            if (oq) {
                int p = __builtin_amdgcn_cvt_pk_fp8_f32(v0, v1, 0, false);
                p = __builtin_amdgcn_cvt_pk_fp8_f32(v2, v3, p, true);
                *(unsigned int*)(oq + base) = (unsigned int)p;
            }
        }
    }
}

// ---------------- MFMA GEMM, fp32 input (layer 1): split x in-register -> fp8 only ----------------

__global__ __launch_bounds__(256) void gemm_mfma_x(
    const float* __restrict__ X, const float* __restrict__ W,
    unsigned char* __restrict__ oq, int n_rows)
{
    const int lane = threadIdx.x & 63;
    const int wv   = threadIdx.x >> 6;
    const int col0 = wv * 32;
    const int l15  = lane & 15;
    const int lg   = lane >> 4;

    bf16x8 whi[2][4], wlo[2][4];
    #pragma unroll
    for (int t = 0; t < 2; t++) {
        int c = col0 + 16 * t + l15;
        #pragma unroll
        for (int ks = 0; ks < 4; ks++) {
            #pragma unroll
            for (int j = 0; j < 8; j++) {
                float wvv = W[(ks * 32 + lg * 8 + j) * 128 + c];
                bf16 h = (bf16)wvv;
                whi[t][ks][j] = h;
                wlo[t][ks][j] = (bf16)(wvv - (float)h);
            }
        }
    }

    const int nrt = n_rows >> 4;
    for (int rt = blockIdx.x; rt < nrt; rt += gridDim.x) {
        const int row = rt * 16 + l15;
        const float* px = X + (size_t)row * 128 + lg * 8;
        bf16x8 Ah[4], Al[4];
        #pragma unroll
        for (int ks = 0; ks < 4; ks++) {
            float4 v0 = *(const float4*)(px + ks * 32);
            float4 v1 = *(const float4*)(px + ks * 32 + 4);
            float vv[8] = {v0.x, v0.y, v0.z, v0.w, v1.x, v1.y, v1.z, v1.w};
            #pragma unroll
            for (int j = 0; j < 8; j++) {
                bf16 h = (bf16)vv[j];
                Ah[ks][j] = h;
                Al[ks][j] = (bf16)(vv[j] - (float)h);
            }
        }
        #pragma unroll
        for (int t = 0; t < 2; t++) {
            f32x4 acc = {0.f, 0.f, 0.f, 0.f};
            #pragma unroll
            for (int ks = 0; ks < 4; ks++) {
                acc = __builtin_amdgcn_mfma_f32_16x16x32_bf16(whi[t][ks], Al[ks], acc, 0, 0, 0);
                acc = __builtin_amdgcn_mfma_f32_16x16x32_bf16(wlo[t][ks], Ah[ks], acc, 0, 0, 0);
                acc = __builtin_amdgcn_mfma_f32_16x16x32_bf16(whi[t][ks], Ah[ks], acc, 0, 0, 0);
            }
            const int c0 = col0 + 16 * t + lg * 4;
            size_t base = (size_t)(rt * 16 + l15) * 128 + c0;
            int p = __builtin_amdgcn_cvt_pk_fp8_f32(acc[0], acc[1], 0, false);
            p = __builtin_amdgcn_cvt_pk_fp8_f32(acc[2], acc[3], p, true);
            *(unsigned int*)(oq + base) = (unsigned int)p;
        }
    }
}

// ---------------- CSR gather aggregation: fp8 hidden state (self + messages), bf16 out ----------------

__global__ __launch_bounds__(256) void gather_agg_split(
    const unsigned char* __restrict__ hq,
    const uint2* __restrict__ erec, const int* __restrict__ off,
    const float* __restrict__ dinv, const float* __restrict__ bias,
    bf16* __restrict__ ohi, int n)
{
    int lane = threadIdx.x & 63;
    int wid  = (blockIdx.x * 256 + threadIdx.x) >> 6;
    int nw   = (gridDim.x * 256) >> 6;

    const int f = 2 * lane;
    float bb0 = bias[f], bb1 = bias[f + 1];

    for (int node = wid; node < n; node += nw) {
        float sn = dinv[node]; sn *= sn;
        size_t nb = (size_t)node * 128 + f;
        unsigned short sq = *(const unsigned short*)(hq + nb);
        f32x2 sv = __builtin_amdgcn_cvt_pk_f32_fp8((int)(unsigned)sq, false);
        float a0 = fmaf(sv[0], sn, bb0);
        float a1 = fmaf(sv[1], sn, bb1);

        int e0 = off[node], e1 = off[node + 1];
        int e = e0;
        for (; e + 8 <= e1; e += 8) {
            uint2 q[8];
            #pragma unroll
            for (int j = 0; j < 8; j++) q[j] = erec[e + j];
            unsigned short rw[8];
            #pragma unroll
            for (int j = 0; j < 8; j++)
                rw[j] = *(const unsigned short*)(hq + (size_t)q[j].x * 128 + f);
            #pragma unroll
            for (int j = 0; j < 8; j++) {
                float w = __uint_as_float(q[j].y);
                f32x2 mv = __builtin_amdgcn_cvt_pk_f32_fp8((int)(unsigned)rw[j], false);
                a0 = fmaf(mv[0], w, a0);
                a1 = fmaf(mv[1], w, a1);
            }
        }
        for (; e + 4 <= e1; e += 4) {
            uint2 q[4];
            #pragma unroll
            for (int j = 0; j < 4; j++) q[j] = erec[e + j];
            unsigned short rw[4];
            #pragma unroll
            for (int j = 0; j < 4; j++)
                rw[j] = *(const unsigned short*)(hq + (size_t)q[j].x * 128 + f);
            #pragma unroll
            for (int j = 0; j < 4; j++) {
                float w = __uint_as_float(q[j].y);
                f32x2 mv = __builtin_amdgcn_cvt_pk_f32_fp8((int)(unsigned)rw[j], false);
                a0 = fmaf(mv[0], w, a0);
                a1 = fmaf(mv[1], w, a1);
            }
        }
        for (; e < e1; e++) {
            uint2 q = erec[e];
            float w = __uint_as_float(q.y);
            unsigned short rwv = *(const unsigned short*)(hq + (size_t)q.x * 128 + f);
            f32x2 mv = __builtin_amdgcn_cvt_pk_f32_fp8((int)(unsigned)rwv, false);
            a0 = fmaf(mv[0], w, a0);
            a1 = fmaf(mv[1], w, a1);
        }

        a0 = fmaxf(a0, 0.f);
        a1 = fmaxf(a1, 0.f);
        bf16x2 oh;
        oh[0] = (bf16)a0;
        oh[1] = (bf16)a1;
        *(bf16x2*)(ohi + nb) = oh;
    }
}

// ---------------- lin2 + log_softmax via MFMA (swapped operands), bf16-hi input ----------------

__global__ __launch_bounds__(256) void lin2_mfma_lsm(
    const bf16* __restrict__ hhi,
    const float* __restrict__ W, const float* __restrict__ bias,
    float* __restrict__ out, int n)
{
    const int lane = threadIdx.x & 63;
    const int l15  = lane & 15;
    const int lg   = lane >> 4;

    bf16x8 whi[3][4], wlo[3][4];
    #pragma unroll
    for (int t = 0; t < 3; t++) {
        int c = t * 16 + l15;
        bool valid = c < 40;
        #pragma unroll
        for (int ks = 0; ks < 4; ks++) {
            #pragma unroll
            for (int j = 0; j < 8; j++) {
                float wv = valid ? W[(ks * 32 + lg * 8 + j) * 40 + c] : 0.f;
                bf16 h = (bf16)wv;
                whi[t][ks][j] = h;
                wlo[t][ks][j] = (bf16)(wv - (float)h);
            }
        }
    }
    f32x4 bb[3];
    bool vstore[3];
    #pragma unroll
    for (int t = 0; t < 3; t++) {
        int c0 = t * 16 + lg * 4;
        vstore[t] = (c0 < 40);
        if (vstore[t]) bb[t] = *(const f32x4*)(bias + c0);
        else bb[t] = (f32x4){0.f, 0.f, 0.f, 0.f};
    }

    int wtile = (blockIdx.x * 256 + threadIdx.x) >> 6;
    int nwt   = (gridDim.x * 256) >> 6;
    int ntiles = (n + 15) >> 4;

    for (int rt = wtile; rt < ntiles; rt += nwt) {
        int arow = rt * 16 + l15;
        if (arow >= n) arow = n - 1;
        const bf16* pah = hhi + (size_t)arow * 128 + lg * 8;
        bf16x8 Ah[4];
        #pragma unroll
        for (int ks = 0; ks < 4; ks++)
            Ah[ks] = *(const bf16x8*)(pah + ks * 32);
        f32x4 acc[3];
        #pragma unroll
        for (int t = 0; t < 3; t++) {
            acc[t] = (f32x4){0.f, 0.f, 0.f, 0.f};
            #pragma unroll
            for (int ks = 0; ks < 4; ks++) {
                acc[t] = __builtin_amdgcn_mfma_f32_16x16x32_bf16(wlo[t][ks], Ah[ks], acc[t], 0, 0, 0);
                acc[t] = __builtin_amdgcn_mfma_f32_16x16x32_bf16(whi[t][ks], Ah[ks], acc[t], 0, 0, 0);
            }
        }
        float m = -INFINITY;
        #pragma unroll
        for (int t = 0; t < 3; t++) {
            if (vstore[t]) {
                #pragma unroll
                for (int r = 0; r < 4; r++) m = fmaxf(m, acc[t][r] + bb[t][r]);
            }
        }
        m = fmaxf(m, __shfl_xor(m, 16, 64));
        m = fmaxf(m, __shfl_xor(m, 32, 64));
        float s = 0.f;
        #pragma unroll
        for (int t = 0; t < 3; t++) {
            if (vstore[t]) {
                #pragma unroll
                for (int r = 0; r < 4; r++) s += __expf(acc[t][r] + bb[t][r] - m);
            }
        }
        s += __shfl_xor(s, 16, 64);
        s += __shfl_xor(s, 32, 64);
        float ls = __logf(s) + m;

        int node = rt * 16 + l15;
        if (node < n) {
            #pragma unroll
            for (int t = 0; t < 3; t++) {
                if (vstore[t]) {
                    f32x4 o;
                    #pragma unroll
                    for (int r = 0; r < 4; r++) o[r] = acc[t][r] + bb[t][r] - ls;
                    *(f32x4*)(out + (size_t)node * 40 + t * 16 + lg * 4) = o;
                }
            }
        }
    }
}

// ---------------- launch ----------------

static inline size_t align256(size_t x) { return (x + 255) & ~(size_t)255; }

extern "C" void kernel_launch(void* const* d_in, const int* in_sizes, int n_in,
                              void* d_out, int out_size, void* d_ws, size_t ws_size,
                              hipStream_t stream)
{
    const float* x   = (const float*)d_in[0];
    const int*   ei  = (const int*)d_in[1];
    const float* W1  = (const float*)d_in[2];  const float* b1  = (const float*)d_in[3];
    const float* W2  = (const float*)d_in[4];  const float* b2  = (const float*)d_in[5];
    const float* W3  = (const float*)d_in[6];  const float* b3  = (const float*)d_in[7];
    const float* l1w = (const float*)d_in[8];  const float* l1b = (const float*)d_in[9];
    const float* l2w = (const float*)d_in[10]; const float* l2b = (const float*)d_in[11];

    const int N = in_sizes[0] / 128;
    const int E = in_sizes[1] / 2;
    const int* src = ei;
    const int* dst = ei + E;

    char* wsb = (char*)d_ws;
    size_t o = 0;
    int*   gcur  = (int*)(wsb + o);   o = align256(o + (size_t)N * 4);        // fill_sort fallback cursors
    int*   off   = (int*)(wsb + o);   o = align256(o + (size_t)(N + 1) * 4);
    int*   bhist = (int*)(wsb + o);   o = align256(o + (size_t)512 * 4);
    int*   bcur  = (int*)(wsb + o);   o = align256(o + (size_t)512 * 4);
    int*   ebase = (int*)(wsb + o);   o = align256(o + (size_t)513 * 4);
    uint2* erec  = (uint2*)(wsb + o); o = align256(o + (size_t)E * 8);
    float* dinv  = (float*)(wsb + o); o = align256(o + (size_t)N * 4);
    bf16*  ahi   = (bf16*)(wsb + o);  o = align256(o + (size_t)N * 128 * 2);
    bf16*  hhi   = (bf16*)(wsb + o);  o = align256(o + (size_t)N * 128 * 2);
    unsigned char* hq = (unsigned char*)(wsb + o); o = align256(o + (size_t)N * 128);

    uint2* ebuf = (uint2*)hhi;   // dead until lin1; 12.8MB < 25.6MB region

    float* outp = (float*)d_out;
    const int nbk  = (N + 255) >> BSH2;                 // 391 buckets
    const int npart = (E + PCH - 1) / PCH;              // 391 chunks

    // ---- CSR build: bucket hist, scan, partition, per-bucket off/dinv(+gcur=0), counting sort ----
    zero_i32<<<4, 256, 0, stream>>>(bhist, 1024);       // bhist + bcur (contiguous)
    bhist_k<<<1024, 256, 0, stream>>>(dst, bhist, E);
    bscan512<<<1, 64, 0, stream>>>(bhist, ebase);
    partition_edges<<<npart, 256, 0, stream>>>(src, dst, ebase, bcur, ebuf, E, nbk);
    bucket_off_dinv<<<nbk, 256, 0, stream>>>(ebuf, ebase, off, dinv, gcur, N, nbk);
    fill_sort<<<nbk, 256, 0, stream>>>(ebuf, off, dinv, gcur, erec, N, nbk);

    // ---- layer 1: gemm from fp32 x -> fp8 hidden state ----
    gemm_mfma_x<<<1024, 256, 0, stream>>>(x, W1, hq, N);
    gather_agg_split<<<4096, 256, 0, stream>>>(hq, erec, off, dinv, b1, ahi, N);

    // ---- layer 2 ----
    gemm_mfma<<<1024, 256, 0, stream>>>(ahi, W2, nullptr, nullptr, hq, N, 0);
    gather_agg_split<<<4096, 256, 0, stream>>>(hq, erec, off, dinv, b2, ahi, N);

    // ---- layer 3 ----
    gemm_mfma<<<1024, 256, 0, stream>>>(ahi, W3, nullptr, nullptr, hq, N, 0);
    gather_agg_split<<<4096, 256, 0, stream>>>(hq, erec, off, dinv, b3, ahi, N);

    // ---- lin1 (+bias+relu) -> bf16 hi (lin2 input) ----
    gemm_mfma<<<1024, 256, 0, stream>>>(ahi, l1w, l1b, hhi, nullptr, N, 1);

    // ---- lin2 + log_softmax ----
    lin2_mfma_lsm<<<512, 256, 0, stream>>>(hhi, l2w, l2b, outp, N);
}